// Round 7
// baseline (215.557 us; speedup 1.0000x reference)
//
#include <hip/hip_runtime.h>
#include <hip/hip_bf16.h>
#include <hip/hip_cooperative_groups.h>

namespace cg = cooperative_groups;

#define L_SEQ 2048
#define NH 16
#define DH 64
#define NCH 32
#define SCALE_F 0.125f
#define EPS_F 1e-4f
#define DN_F 0.35355339059327373f      // sqrt(0.125)
#define HLM_F 1.5890269151739727f      // 0.5*log(24)

typedef __attribute__((ext_vector_type(8))) short short8v;   // 8 bf16 (MFMA A/B frag)
typedef __attribute__((ext_vector_type(4))) float f32x4;     // MFMA C/D frag

// round-to-nearest-even f32 -> bf16
__device__ __forceinline__ unsigned short f2bf(float x) {
  unsigned u = __float_as_uint(x);
  u += 0x7FFFu + ((u >> 16) & 1u);
  return (unsigned short)(u >> 16);
}
__device__ __forceinline__ unsigned pk2(float a, float b) {
  return (unsigned)f2bf(a) | ((unsigned)f2bf(b) << 16);
}
__device__ __forceinline__ float stab_from_pmax(const float* __restrict__ pmax, int h, int t) {
  float v = pmax[h * 32 + (t & 31)];
  v = fmaxf(v, __shfl_xor(v, 1));  v = fmaxf(v, __shfl_xor(v, 2));
  v = fmaxf(v, __shfl_xor(v, 4));  v = fmaxf(v, __shfl_xor(v, 8));
  v = fmaxf(v, __shfl_xor(v, 16));
  return v;
}

#define LDS_BYTES 80512

// ======================= FUSED cooperative kernel =======================
// Block (b,h) owns 64-row chunk b of head h. Static LDS (no dynamic-shared cap).
__global__ __launch_bounds__(256, 2) void fused_attn(
    const float* __restrict__ qkv, const float* __restrict__ proj,
    float* __restrict__ pmax, unsigned* __restrict__ kbw,
    unsigned* __restrict__ kpw, float* __restrict__ kpfx,
    float* __restrict__ kvs, unsigned* __restrict__ vtw,
    float* __restrict__ out)
{
  __shared__ __align__(16) char lds[LDS_BYTES];
  char* A  = lds;                       // 24576: p1 sX f32 [0,16K) + own-K bf16 [16K,24K); p2 sV; p3 K then W
  char* B  = lds + 24576;               // 12288: k' bf16 192x64B (own at +8192); late: KVexcl^T
  char* C  = lds + 36864;               // 8192: own Q bf16 (persistent p1->p3)
  char* D  = lds + 45056;               // 8192: p1 sP f32[24][68]; p3 V^T staging
  char* E  = lds + 53248;               // 8192: own V^T bf16 (persistent p2->p3)
  char* F  = lds + 61440;               // 4096: q' bf16 (persistent)
  float* G = (float*)(lds + 65536);     // 6144: q' f32 [64][24] (persistent)
  float* H = (float*)(lds + 71680);     // 6656: p2 sKpF f32[64][25]; p3 sPfx f32[1536]
  float* sRed  = (float*)(lds + 78336); // 1024
  float* qlogA = (float*)(lds + 79360); // 256
  float* sKcx  = (float*)(lds + 79616); // 128
  float* sSum  = (float*)(lds + 79744); // 256
  float* sGps  = (float*)(lds + 80000); // 256
  float* sRin  = (float*)(lds + 80256); // 256

  const int b = blockIdx.x, h = blockIdx.y, t = threadIdx.x;
  const int r4 = t >> 2, mg = t & 3;
  cg::grid_group grid = cg::this_grid();

  // ================= PHASE 1: features =================
  float* sP = (float*)D;
  float* sX = (float*)A;                // [64][64], float4 slot q at q^(r&15)
  for (int i = t; i < 1536; i += 256) sP[(i >> 6) * 68 + (i & 63)] = proj[i];

  float kd[6];
  float sqk = 0.f;
  float lmax = -1e30f;

  for (int qk = 0; qk < 2; ++qk) {
    const int slot = qk ? 0 : 1;        // first K (slot1), then Q (slot0)
    __syncthreads();
    for (int i = t; i < 1024; i += 256) {
      int rr = i >> 4, q = i & 15;
      int l = b * 64 + rr;
      *(float4*)&sX[rr * 64 + 4 * (q ^ (rr & 15))] =
          *(const float4*)(qkv + (((size_t)l * 3 + slot) * NH + h) * DH + 4 * q);
    }
    __syncthreads();
    for (int w = t; w < 2048; w += 256) {
      int rr = w >> 5, wo = w & 31;
      int q = wo >> 1, sub = (wo & 1) * 2;
      const float* px = &sX[rr * 64 + 4 * (q ^ (rr & 15)) + sub];
      unsigned word = pk2(px[0], px[1]);
      int swo = wo ^ ((rr & 7) << 2);
      if (qk == 0) {
        kbw[((size_t)h * L_SEQ + b * 64 + rr) * 32 + swo] = word;
        *(unsigned*)(A + 16384 + rr * 128 + 4 * swo) = word;
      } else {
        *(unsigned*)(C + rr * 128 + 4 * swo) = word;
      }
    }
    float acc[6] = {0.f, 0.f, 0.f, 0.f, 0.f, 0.f};
    float sq = 0.f;
    for (int d4 = 0; d4 < 16; ++d4) {
      float4 xv = *(const float4*)&sX[r4 * 64 + 4 * (d4 ^ (r4 & 15))];
      sq += xv.x * xv.x; sq += xv.y * xv.y; sq += xv.z * xv.z; sq += xv.w * xv.w;
#pragma unroll
      for (int i = 0; i < 6; ++i) {
        float4 pv = *(const float4*)&sP[(mg * 6 + i) * 68 + d4 * 4];
        acc[i] += xv.x * pv.x; acc[i] += xv.y * pv.y;
        acc[i] += xv.z * pv.z; acc[i] += xv.w * pv.w;
      }
    }
    if (qk == 0) {
#pragma unroll
      for (int i = 0; i < 6; ++i) { kd[i] = acc[i] * DN_F; lmax = fmaxf(lmax, kd[i]); }
      sqk = sq;
    } else {
      float qd6[6]; float mx = -1e30f;
#pragma unroll
      for (int i = 0; i < 6; ++i) { qd6[i] = acc[i] * DN_F; mx = fmaxf(mx, qd6[i]); }
      mx = fmaxf(mx, __shfl_xor(mx, 1));
      mx = fmaxf(mx, __shfl_xor(mx, 2));
      float qpv[6];
#pragma unroll
      for (int i = 0; i < 6; ++i) {
        qpv[i] = __expf(qd6[i] - mx) + EPS_F;
        G[r4 * 24 + mg * 6 + i] = qpv[i];
      }
#pragma unroll
      for (int j = 0; j < 3; ++j)
        *(unsigned*)(F + r4 * 64 + 4 * ((3 * mg + j) ^ ((r4 & 3) << 2))) = pk2(qpv[2 * j], qpv[2 * j + 1]);
      if (mg == 0) {
#pragma unroll
        for (int j = 0; j < 4; ++j)
          *(unsigned*)(F + r4 * 64 + 4 * ((12 + j) ^ ((r4 & 3) << 2))) = 0u;
        qlogA[r4] = mx - 0.5f * SCALE_F * sq - HLM_F;
      }
    }
  }
  sRed[t] = lmax;
  __syncthreads();
#pragma unroll
  for (int s = 128; s > 0; s >>= 1) {
    if (t < s) sRed[t] = fmaxf(sRed[t], sRed[t + s]);
    __syncthreads();
  }
  if (t == 0) pmax[h * 32 + b] = sRed[0];

  grid.sync();

  // ================= PHASE 2: k', kpfx, kvs, V^T =================
  const float stab = stab_from_pmax(pmax, h, t);
  float* sV = (float*)A;
  for (int i = t; i < 1024; i += 256) {
    int rr = i >> 4, q = i & 15;
    int l = b * 64 + rr;
    *(float4*)&sV[rr * 64 + 4 * (q ^ (rr & 15))] =
        *(const float4*)(qkv + (((size_t)l * 3 + 2) * NH + h) * DH + 4 * q);
  }
  float* sKpF = H;
  {
    float kn = 0.5f * SCALE_F * sqk;
    float kp6[6];
#pragma unroll
    for (int i = 0; i < 6; ++i) {
      kp6[i] = __expf(kd[i] - kn - stab) + EPS_F;
      sKpF[r4 * 25 + mg * 6 + i] = kp6[i];
    }
#pragma unroll
    for (int j = 0; j < 3; ++j) {
      unsigned word = pk2(kp6[2 * j], kp6[2 * j + 1]);
      int swo = (3 * mg + j) ^ ((r4 & 3) << 2);
      kpw[((size_t)h * L_SEQ + b * 64 + r4) * 16 + swo] = word;
      *(unsigned*)(B + 8192 + r4 * 64 + 4 * swo) = word;
    }
    if (mg == 0) {
#pragma unroll
      for (int j = 0; j < 4; ++j) {
        int swo = (12 + j) ^ ((r4 & 3) << 2);
        kpw[((size_t)h * L_SEQ + b * 64 + r4) * 16 + swo] = 0u;
        *(unsigned*)(B + 8192 + r4 * 64 + 4 * swo) = 0u;
      }
    }
  }
  __syncthreads();
  for (int w = t; w < 2048; w += 256) {
    int d = w >> 5, jp = w & 31;
    int ra = 2 * jp, rb = 2 * jp + 1, q = d >> 2, s4 = d & 3;
    float va = sV[ra * 64 + 4 * (q ^ (ra & 15)) + s4];
    float vb = sV[rb * 64 + 4 * (q ^ (rb & 15)) + s4];
    unsigned word = pk2(va, vb);
    int swo = jp ^ ((d & 7) << 2);
    vtw[((size_t)h * NCH + b) * 2048 + d * 32 + swo] = word;
    *(unsigned*)(E + d * 128 + 4 * swo) = word;
  }
  if (t < 192) {
    const int m = t % 24, dO = (t / 24) * 8;
    const int s0 = dO >> 2, s1 = s0 + 1;
    float a0x = 0.f, a0y = 0.f, a0z = 0.f, a0w = 0.f;
    float a1x = 0.f, a1y = 0.f, a1z = 0.f, a1w = 0.f;
    for (int r2 = 0; r2 < 64; ++r2) {
      float kp = sKpF[r2 * 25 + m];
      float4 v0 = *(const float4*)&sV[r2 * 64 + 4 * (s0 ^ (r2 & 15))];
      float4 v1 = *(const float4*)&sV[r2 * 64 + 4 * (s1 ^ (r2 & 15))];
      a0x += kp * v0.x; a0y += kp * v0.y; a0z += kp * v0.z; a0w += kp * v0.w;
      a1x += kp * v1.x; a1y += kp * v1.y; a1z += kp * v1.z; a1w += kp * v1.w;
    }
    float* dst = kvs + ((size_t)h * NCH + b) * 1536 + m * 64 + dO;
    float4 o0 = {a0x, a0y, a0z, a0w};
    float4 o1 = {a1x, a1y, a1z, a1w};
    *(float4*)dst = o0;
    *(float4*)(dst + 4) = o1;
  }
  if (t < 24) {
    float run = 0.f;
    for (int r2 = 0; r2 < 64; ++r2) {
      run += sKpF[r2 * 25 + t];
      kpfx[((size_t)h * L_SEQ + b * 64 + r2) * 24 + t] = run;
    }
  }

  grid.sync();

  // ================= PHASE 3: fused attention =================
  const int wv = t >> 6, lane = t & 63, g = lane >> 4, ln = lane & 15;
  const int keybase = b * 64 - 128;
  const int jmin = (b >= 2) ? 0 : (128 - 64 * b);
  const int rA = wv * 16 + ln;

  for (int w = t; w < 1024; w += 256) {
    int r = w >> 3, q4 = w & 7;
    int l = keybase + r; l = l < 0 ? 0 : l;
    *(uint4*)(A + r * 128 + q4 * 16) = *(const uint4*)(kbw + ((size_t)h * L_SEQ + l) * 32 + q4 * 4);
  }
  for (int w = t; w < 512; w += 256) {
    int r = w >> 2, q4 = w & 3;
    int l = keybase + r; l = l < 0 ? 0 : l;
    *(uint4*)(B + r * 64 + q4 * 16) = *(const uint4*)(kpw + ((size_t)h * L_SEQ + l) * 16 + q4 * 4);
  }
  {
    float accp[6] = {0.f, 0.f, 0.f, 0.f, 0.f, 0.f};
    const float* srcb = kvs + (size_t)h * NCH * 1536 + t;
    int bp = 0;
    for (; bp + 4 <= b; bp += 4) {
      float v0[6], v1[6], v2[6], v3[6];
#pragma unroll
      for (int j = 0; j < 6; ++j) v0[j] = srcb[(size_t)(bp + 0) * 1536 + j * 256];
#pragma unroll
      for (int j = 0; j < 6; ++j) v1[j] = srcb[(size_t)(bp + 1) * 1536 + j * 256];
#pragma unroll
      for (int j = 0; j < 6; ++j) v2[j] = srcb[(size_t)(bp + 2) * 1536 + j * 256];
#pragma unroll
      for (int j = 0; j < 6; ++j) v3[j] = srcb[(size_t)(bp + 3) * 1536 + j * 256];
#pragma unroll
      for (int j = 0; j < 6; ++j) {
        accp[j] += v0[j]; accp[j] += v1[j]; accp[j] += v2[j]; accp[j] += v3[j];
      }
    }
    for (; bp < b; ++bp) {
#pragma unroll
      for (int j = 0; j < 6; ++j) accp[j] += srcb[(size_t)bp * 1536 + j * 256];
    }
#pragma unroll
    for (int j = 0; j < 6; ++j) H[t + j * 256] = accp[j];
  }
  if (t < 24) {
    float runk = 0.f;
    for (int bp = 0; bp < b; ++bp)
      runk += kpfx[((size_t)h * L_SEQ + bp * 64 + 63) * 24 + t];
    sKcx[t] = runk;
  }
  __syncthreads();

  float eF[12][4];
  float rs[4] = {0.f, 0.f, 0.f, 0.f};
  short8v aS0 = *(const short8v*)(C + (rA * 128 + ((g * 16) ^ ((rA & 7) << 4))));
  short8v aS1 = *(const short8v*)(C + (rA * 128 + ((64 + g * 16) ^ ((rA & 7) << 4))));
#pragma unroll
  for (int nt = 0; nt < 12; ++nt) {
    int rB = nt * 16 + ln;
    short8v b0 = *(const short8v*)(A + (rB * 128 + ((g * 16) ^ ((rB & 7) << 4))));
    short8v b1 = *(const short8v*)(A + (rB * 128 + ((64 + g * 16) ^ ((rB & 7) << 4))));
    f32x4 acc = {0.f, 0.f, 0.f, 0.f};
    acc = __builtin_amdgcn_mfma_f32_16x16x32_bf16(aS0, b0, acc, 0, 0, 0);
    acc = __builtin_amdgcn_mfma_f32_16x16x32_bf16(aS1, b1, acc, 0, 0, 0);
    int j = nt * 16 + ln;
#pragma unroll
    for (int reg = 0; reg < 4; ++reg) {
      int rl = wv * 16 + g * 4 + reg;
      float e = 0.f;
      if (j >= rl && j <= rl + 128 && j >= jmin) e = __expf(SCALE_F * acc[reg]);
      eF[nt][reg] = e;
      rs[reg] += e;
    }
  }
#pragma unroll
  for (int reg = 0; reg < 4; ++reg) {
    float v = rs[reg];
    v += __shfl_xor(v, 1); v += __shfl_xor(v, 2);
    v += __shfl_xor(v, 4); v += __shfl_xor(v, 8);
    if (ln == 0) sSum[wv * 16 + g * 4 + reg] = v;
  }

  float pF[12][4];
  short8v aP = *(const short8v*)(F + (rA * 64 + ((g * 16) ^ ((rA & 3) << 4))));
#pragma unroll
  for (int nt = 0; nt < 12; ++nt) {
    int rB = nt * 16 + ln;
    short8v bp = *(const short8v*)(B + (rB * 64 + ((g * 16) ^ ((rB & 3) << 4))));
    f32x4 acc = {0.f, 0.f, 0.f, 0.f};
    acc = __builtin_amdgcn_mfma_f32_16x16x32_bf16(aP, bp, acc, 0, 0, 0);
#pragma unroll
    for (int reg = 0; reg < 4; ++reg) pF[nt][reg] = acc[reg];
  }
  __syncthreads();

  if (t < 64) {
    int r = t, l = b * 64 + r;
    const float* kfc = kpfx + ((size_t)h * L_SEQ + l) * 24;
    int b1i = (b >= 1) ? b - 1 : 0;
    int b2i = (b >= 2) ? b - 2 : 0;
    int rm1 = (r >= 1) ? r - 1 : 0;
    const float* T1p = kpfx + ((size_t)h * L_SEQ + b1i * 64 + 63) * 24;
    const float* T2p = kpfx + ((size_t)h * L_SEQ + b2i * 64 + 63) * 24;
    const float* S2p = kpfx + ((size_t)h * L_SEQ + b2i * 64 + rm1) * 24;
    float f1 = (b >= 1) ? 1.f : 0.f;
    float f2 = (b >= 2) ? 1.f : 0.f;
    float fr = (b >= 2 && r >= 1) ? 1.f : 0.f;
    float psc = 0.f, kcs = 0.f, bnd = 0.f;
#pragma unroll
    for (int m = 0; m < 24; ++m) {
      float qp = G[r * 24 + m];
      float kc = kfc[m];
      psc += qp * kc;
      kcs += qp * sKcx[m];
      bnd += qp * (kc + f1 * T1p[m] + f2 * T2p[m] - fr * S2p[m]);
    }
    float goc = kcs + psc;
    float gqk = SCALE_F * bnd;
    float se = sSum[r];
    float lse = __logf(se);
    float gscale = qlogA[r] + stab - HLM_F;
    float gln = __logf(fmaxf(goc - gqk, 1e-24f)) + gscale;
    float mx2 = fmaxf(lse, gln), mn2 = fminf(lse, gln);
    float lognorm = mx2 + log1pf(__expf(mn2 - mx2));
    sGps[r] = __expf(gscale - lognorm);
    sRin[r] = 1.f / se;
  }
  __syncthreads();

  float gpr[4], rin[4];
#pragma unroll
  for (int reg = 0; reg < 4; ++reg) {
    int rl = wv * 16 + g * 4 + reg;
    gpr[reg] = sGps[rl];
    rin[reg] = sRin[rl];
  }
#pragma unroll
  for (int nt = 0; nt < 12; ++nt) {
    int j = nt * 16 + ln;
#pragma unroll
    for (int reg = 0; reg < 4; ++reg) {
      int rl = wv * 16 + g * 4 + reg;
      bool causal = (j >= 128) && (j <= 128 + rl);
      bool bprev = (j >= rl) && (j < 128) && (j >= jmin);
      float coef = causal ? (1.f - SCALE_F) * gpr[reg] : (bprev ? -SCALE_F * gpr[reg] : 0.f);
      float wgt = eF[nt][reg] * rin[reg] + coef * pF[nt][reg];
      float wn = __shfl_xor(wgt, 1);
      if ((ln & 1) == 0) {
        *(unsigned*)(A + (rl * 384 + ((j * 2) ^ ((rl & 7) << 4)))) = pk2(wgt, wn);
      }
    }
  }
  __syncthreads();

  for (int w = t; w < 1024; w += 256) {
    int d = w >> 4, mp = w & 15;
    int m0 = 2 * mp, m1 = m0 + 1;
    float a = (m0 < 24) ? H[m0 * 64 + d] : 0.f;
    float bb = (m1 < 24) ? H[m1 * 64 + d] : 0.f;
    *(unsigned*)(B + (d * 64 + ((mp * 4) ^ ((d & 3) << 4)))) = pk2(a, bb);
  }

  f32x4 oF[4];
#pragma unroll
  for (int dt = 0; dt < 4; ++dt) { f32x4 z = {0.f, 0.f, 0.f, 0.f}; oF[dt] = z; }
  for (int vt3 = 0; vt3 < 3; ++vt3) {
    const char* vbase;
    if (vt3 < 2) {
      int lt = b - 2 + vt3; lt = lt < 0 ? 0 : lt;
      for (int w = t; w < 512; w += 256)
        *(uint4*)(D + w * 16) = *(const uint4*)(vtw + ((size_t)h * NCH + lt) * 2048 + w * 4);
      vbase = D;
    } else {
      vbase = E;
    }
    __syncthreads();
#pragma unroll
    for (int ks = 0; ks < 2; ++ks) {
      short8v aw = *(const short8v*)(A + (rA * 384 + ((vt3 * 128 + ks * 64 + g * 16) ^ ((rA & 7) << 4))));
#pragma unroll
      for (int dt = 0; dt < 4; ++dt) {
        int rB = dt * 16 + ln;
        short8v bv = *(const short8v*)(vbase + (rB * 128 + ((ks * 64 + g * 16) ^ ((rB & 7) << 4))));
        oF[dt] = __builtin_amdgcn_mfma_f32_16x16x32_bf16(aw, bv, oF[dt], 0, 0, 0);
      }
    }
    __syncthreads();
  }

  short8v aq = *(const short8v*)(F + (rA * 64 + ((g * 16) ^ ((rA & 3) << 4))));
  f32x4 ogF[4];
#pragma unroll
  for (int dt = 0; dt < 4; ++dt) {
    int rB = dt * 16 + ln;
    short8v bg = *(const short8v*)(B + (rB * 64 + ((g * 16) ^ ((rB & 3) << 4))));
    f32x4 z = {0.f, 0.f, 0.f, 0.f};
    ogF[dt] = __builtin_amdgcn_mfma_f32_16x16x32_bf16(aq, bg, z, 0, 0, 0);
  }

#pragma unroll
  for (int dt = 0; dt < 4; ++dt) {
    int d = dt * 16 + ln;
#pragma unroll
    for (int reg = 0; reg < 4; ++reg) {
      int rl = wv * 16 + g * 4 + reg;
      int l = b * 64 + rl;
      out[((size_t)l * NH + h) * DH + d] = oF[dt][reg] + gpr[reg] * ogF[dt][reg];
    }
  }
}

// ======================= FALLBACK: verified round-5 path =======================
__global__ __launch_bounds__(256) void k1_feat(
    const float* __restrict__ qkv, const float* __restrict__ proj,
    float* __restrict__ kdash, float* __restrict__ knorm,
    float* __restrict__ qdash, float* __restrict__ qnorm,
    float* __restrict__ pmax, unsigned* __restrict__ kbw, unsigned* __restrict__ qbw)
{
  __shared__ __attribute__((aligned(16))) float sP[24][68];
  __shared__ __attribute__((aligned(16))) float sX[64][68];
  __shared__ float sRed[256];
  const int c = blockIdx.x, h = blockIdx.y, t = threadIdx.x;
  for (int i = t; i < 24 * 64; i += 256) sP[i >> 6][i & 63] = proj[i];
  float lmax = -1e30f;
  const int r = t >> 2, mg = t & 3;
  for (int qk = 0; qk < 2; ++qk) {
    const int slot = qk ? 0 : 1;
    __syncthreads();
    for (int i = t; i < 1024; i += 256) {
      int rr = i >> 4, d4 = (i & 15) * 4;
      int l = c * 64 + rr;
      *(float4*)&sX[rr][d4] = *(const float4*)(qkv + (((size_t)l * 3 + slot) * NH + h) * DH + d4);
    }
    __syncthreads();
    unsigned* dstw = qk ? qbw : kbw;
    for (int w = t; w < 2048; w += 256) {
      int rr = w >> 5, wo = w & 31;
      int l = c * 64 + rr;
      float2 xv = *(const float2*)&sX[rr][2 * wo];
      dstw[((size_t)h * L_SEQ + l) * 32 + (wo ^ ((rr & 7) << 2))] = pk2(xv.x, xv.y);
    }
    float acc[6] = {0.f, 0.f, 0.f, 0.f, 0.f, 0.f};
    float sq = 0.f;
    for (int d4 = 0; d4 < 16; ++d4) {
      float4 xv = *(const float4*)&sX[r][d4 * 4];
      sq += xv.x * xv.x; sq += xv.y * xv.y; sq += xv.z * xv.z; sq += xv.w * xv.w;
#pragma unroll
      for (int i = 0; i < 6; ++i) {
        float4 pv = *(const float4*)&sP[mg * 6 + i][d4 * 4];
        acc[i] += xv.x * pv.x; acc[i] += xv.y * pv.y;
        acc[i] += xv.z * pv.z; acc[i] += xv.w * pv.w;
      }
    }
    int l = c * 64 + r;
    float* dsh = qk ? qdash : kdash;
#pragma unroll
    for (int i = 0; i < 6; ++i) {
      float v = acc[i] * DN_F;
      dsh[((size_t)h * L_SEQ + l) * 24 + mg * 6 + i] = v;
      if (!qk) lmax = fmaxf(lmax, v);
    }
    if (mg == 0) (qk ? qnorm : knorm)[h * L_SEQ + l] = 0.5f * SCALE_F * sq;
  }
  sRed[t] = lmax;
  __syncthreads();
#pragma unroll
  for (int s = 128; s > 0; s >>= 1) {
    if (t < s) sRed[t] = fmaxf(sRed[t], sRed[t + s]);
    __syncthreads();
  }
  if (t == 0) pmax[h * 32 + c] = sRed[0];
}

__global__ __launch_bounds__(256) void k3_kprime(
    const float* __restrict__ qkv, const float* __restrict__ kdash,
    const float* __restrict__ knorm, const float* __restrict__ pmax,
    unsigned* __restrict__ kpw, float* __restrict__ kpfx, float* __restrict__ kvs,
    unsigned* __restrict__ vtw)
{
  __shared__ float sKp[64][25];
  __shared__ __attribute__((aligned(16))) float sV[64][68];
  const int c = blockIdx.x, h = blockIdx.y, t = threadIdx.x;
  const float stab = stab_from_pmax(pmax, h, t);
  for (int i = t; i < 1024; i += 256) {
    int rr = i >> 4, d4 = (i & 15) * 4;
    int l = c * 64 + rr;
    *(float4*)&sV[rr][d4] = *(const float4*)(qkv + (((size_t)l * 3 + 2) * NH + h) * DH + d4);
  }
  for (int i = t; i < 1536; i += 256) {
    int r = i / 24, m = i % 24;
    int l = c * 64 + r;
    sKp[r][m] = __expf(kdash[((size_t)h * L_SEQ + l) * 24 + m] - knorm[h * L_SEQ + l] - stab) + EPS_F;
  }
  __syncthreads();
  for (int w = t; w < 1024; w += 256) {
    int r = w >> 4, wo = w & 15;
    int l = c * 64 + r;
    float a = (wo < 12) ? sKp[r][2 * wo] : 0.f;
    float bb = (wo < 12) ? sKp[r][2 * wo + 1] : 0.f;
    kpw[((size_t)h * L_SEQ + l) * 16 + (wo ^ ((r & 3) << 2))] = pk2(a, bb);
  }
  for (int w = t; w < 2048; w += 256) {
    int d = w >> 5, jp = w & 31;
    vtw[((size_t)h * NCH + c) * 2048 + d * 32 + (jp ^ ((d & 7) << 2))] = pk2(sV[2 * jp][d], sV[2 * jp + 1][d]);
  }
  if (t < 192) {
    const int m = t % 24, dO = (t / 24) * 8;
    float a0x = 0.f, a0y = 0.f, a0z = 0.f, a0w = 0.f;
    float a1x = 0.f, a1y = 0.f, a1z = 0.f, a1w = 0.f;
    for (int r2 = 0; r2 < 64; ++r2) {
      float kp = sKp[r2][m];
      float4 v0 = *(const float4*)&sV[r2][dO];
      float4 v1 = *(const float4*)&sV[r2][dO + 4];
      a0x += kp * v0.x; a0y += kp * v0.y; a0z += kp * v0.z; a0w += kp * v0.w;
      a1x += kp * v1.x; a1y += kp * v1.y; a1z += kp * v1.z; a1w += kp * v1.w;
    }
    float* dst = kvs + ((size_t)h * NCH + c) * 1536 + m * 64 + dO;
    float4 o0 = {a0x, a0y, a0z, a0w};
    float4 o1 = {a1x, a1y, a1z, a1w};
    *(float4*)dst = o0;
    *(float4*)(dst + 4) = o1;
  }
  if (t < 24) {
    float run = 0.f;
    for (int r2 = 0; r2 < 64; ++r2) {
      run += sKp[r2][t];
      kpfx[((size_t)h * L_SEQ + c * 64 + r2) * 24 + t] = run;
    }
  }
}

__global__ __launch_bounds__(256, 2) void k6_attn(
    const unsigned* __restrict__ kpw, const float* __restrict__ kpfx,
    const float* __restrict__ kvs, const unsigned* __restrict__ vtw,
    const float* __restrict__ qdash, const float* __restrict__ qnorm,
    const float* __restrict__ pmax, const unsigned* __restrict__ kbw,
    const unsigned* __restrict__ qbw, float* __restrict__ out)
{
  __shared__ __attribute__((aligned(16))) char lds[62304];
  char* sKW = lds;
  char* sKp = lds + 24576;
  char* sQV = lds + 36864;
  char* sQp = lds + 45056;
  float* sQpF = (float*)(lds + 49152);
  float* sSum = (float*)(lds + 55296);
  float* sGps = sSum + 64;
  float* sRin = sGps + 64;
  float* sKcx = (float*)(lds + 56064);
  float* sPfx = (float*)(lds + 56160);

  const int b = blockIdx.x, h = blockIdx.y, t = threadIdx.x;
  const int wv = t >> 6, lane = t & 63, g = lane >> 4, ln = lane & 15;
  const int keybase = b * 64 - 128;
  const int jmin = (b >= 2) ? 0 : (128 - 64 * b);
  const int rA = wv * 16 + ln;

  for (int w = t; w < 1536; w += 256) {
    int r = w >> 3, q4 = w & 7;
    int l = keybase + r; l = l < 0 ? 0 : l;
    *(uint4*)(sKW + r * 128 + q4 * 16) = *(const uint4*)(kbw + ((size_t)h * L_SEQ + l) * 32 + q4 * 4);
  }
  for (int w = t; w < 512; w += 256) {
    int r = w >> 3, q4 = w & 7;
    int l = b * 64 + r;
    *(uint4*)(sQV + r * 128 + q4 * 16) = *(const uint4*)(qbw + ((size_t)h * L_SEQ + l) * 32 + q4 * 4);
  }
  for (int w = t; w < 768; w += 256) {
    int r = w >> 2, q4 = w & 3;
    int l = keybase + r; l = l < 0 ? 0 : l;
    *(uint4*)(sKp + r * 64 + q4 * 16) = *(const uint4*)(kpw + ((size_t)h * L_SEQ + l) * 16 + q4 * 4);
  }
  const float stab = stab_from_pmax(pmax, h, t);
  {
    float accp[6] = {0.f, 0.f, 0.f, 0.f, 0.f, 0.f};
    const float* srcb = kvs + (size_t)h * NCH * 1536 + t;
    int bp = 0;
    for (; bp + 4 <= b; bp += 4) {
      float v0[6], v1[6], v2[6], v3[6];
#pragma unroll
      for (int j = 0; j < 6; ++j) v0[j] = srcb[(size_t)(bp + 0) * 1536 + j * 256];
#pragma unroll
      for (int j = 0; j < 6; ++j) v1[j] = srcb[(size_t)(bp + 1) * 1536 + j * 256];
#pragma unroll
      for (int j = 0; j < 6; ++j) v2[j] = srcb[(size_t)(bp + 2) * 1536 + j * 256];
#pragma unroll
      for (int j = 0; j < 6; ++j) v3[j] = srcb[(size_t)(bp + 3) * 1536 + j * 256];
#pragma unroll
      for (int j = 0; j < 6; ++j) {
        accp[j] += v0[j]; accp[j] += v1[j]; accp[j] += v2[j]; accp[j] += v3[j];
      }
    }
    for (; bp < b; ++bp) {
#pragma unroll
      for (int j = 0; j < 6; ++j) accp[j] += srcb[(size_t)bp * 1536 + j * 256];
    }
#pragma unroll
    for (int j = 0; j < 6; ++j) sPfx[t + j * 256] = accp[j];
  }
  if (t < 24) {
    float runk = 0.f;
    for (int bp = 0; bp < b; ++bp)
      runk += kpfx[((size_t)h * L_SEQ + bp * 64 + 63) * 24 + t];
    sKcx[t] = runk;
  }
  float qlog = 0.f;
  if (t < 64) {
    int r = t, l = b * 64 + r;
    const float* qdp = qdash + ((size_t)h * L_SEQ + l) * 24;
    float qd[24], mx = -1e30f;
#pragma unroll
    for (int m = 0; m < 24; ++m) { qd[m] = qdp[m]; mx = fmaxf(mx, qd[m]); }
    float qpv[24];
#pragma unroll
    for (int m = 0; m < 24; ++m) { qpv[m] = __expf(qd[m] - mx) + EPS_F; sQpF[r * 24 + m] = qpv[m]; }
    qlog = mx - qnorm[h * L_SEQ + l] - HLM_F;
#pragma unroll
    for (int wo = 0; wo < 16; ++wo) {
      float a = (wo < 12) ? qpv[2 * wo] : 0.f;
      float bb = (wo < 12) ? qpv[2 * wo + 1] : 0.f;
      *(unsigned*)(sQp + (r * 64 + (((wo * 4)) ^ ((r & 3) << 4)))) = pk2(a, bb);
    }
  }
  __syncthreads();

  float eF[12][4];
  float rs[4] = {0.f, 0.f, 0.f, 0.f};
  short8v aS0 = *(const short8v*)(sQV + (rA * 128 + ((g * 16) ^ ((rA & 7) << 4))));
  short8v aS1 = *(const short8v*)(sQV + (rA * 128 + ((64 + g * 16) ^ ((rA & 7) << 4))));
#pragma unroll
  for (int nt = 0; nt < 12; ++nt) {
    int rB = nt * 16 + ln;
    short8v b0 = *(const short8v*)(sKW + (rB * 128 + ((g * 16) ^ ((rB & 7) << 4))));
    short8v b1 = *(const short8v*)(sKW + (rB * 128 + ((64 + g * 16) ^ ((rB & 7) << 4))));
    f32x4 acc = {0.f, 0.f, 0.f, 0.f};
    acc = __builtin_amdgcn_mfma_f32_16x16x32_bf16(aS0, b0, acc, 0, 0, 0);
    acc = __builtin_amdgcn_mfma_f32_16x16x32_bf16(aS1, b1, acc, 0, 0, 0);
    int j = nt * 16 + ln;
#pragma unroll
    for (int reg = 0; reg < 4; ++reg) {
      int rl = wv * 16 + g * 4 + reg;
      float e = 0.f;
      if (j >= rl && j <= rl + 128 && j >= jmin) e = __expf(SCALE_F * acc[reg]);
      eF[nt][reg] = e;
      rs[reg] += e;
    }
  }
#pragma unroll
  for (int reg = 0; reg < 4; ++reg) {
    float v = rs[reg];
    v += __shfl_xor(v, 1); v += __shfl_xor(v, 2);
    v += __shfl_xor(v, 4); v += __shfl_xor(v, 8);
    if (ln == 0) sSum[wv * 16 + g * 4 + reg] = v;
  }

  float pF[12][4];
  short8v aP = *(const short8v*)(sQp + (rA * 64 + ((g * 16) ^ ((rA & 3) << 4))));
#pragma unroll
  for (int nt = 0; nt < 12; ++nt) {
    int rB = nt * 16 + ln;
    short8v bp = *(const short8v*)(sKp + (rB * 64 + ((g * 16) ^ ((rB & 3) << 4))));
    f32x4 acc = {0.f, 0.f, 0.f, 0.f};
    acc = __builtin_amdgcn_mfma_f32_16x16x32_bf16(aP, bp, acc, 0, 0, 0);
#pragma unroll
    for (int reg = 0; reg < 4; ++reg) pF[nt][reg] = acc[reg];
  }
  __syncthreads();

  if (t < 64) {
    int r = t, l = b * 64 + r;
    const float* kfc = kpfx + ((size_t)h * L_SEQ + l) * 24;
    int b1i = (b >= 1) ? b - 1 : 0;
    int b2i = (b >= 2) ? b - 2 : 0;
    int rm1 = (r >= 1) ? r - 1 : 0;
    const float* T1p = kpfx + ((size_t)h * L_SEQ + b1i * 64 + 63) * 24;
    const float* T2p = kpfx + ((size_t)h * L_SEQ + b2i * 64 + 63) * 24;
    const float* S2p = kpfx + ((size_t)h * L_SEQ + b2i * 64 + rm1) * 24;
    float f1 = (b >= 1) ? 1.f : 0.f;
    float f2 = (b >= 2) ? 1.f : 0.f;
    float fr = (b >= 2 && r >= 1) ? 1.f : 0.f;
    float psc = 0.f, kcs = 0.f, bnd = 0.f;
#pragma unroll
    for (int m = 0; m < 24; ++m) {
      float qp = sQpF[r * 24 + m];
      float kc = kfc[m];
      psc += qp * kc;
      kcs += qp * sKcx[m];
      bnd += qp * (kc + f1 * T1p[m] + f2 * T2p[m] - fr * S2p[m]);
    }
    float goc = kcs + psc;
    float gqk = SCALE_F * bnd;
    float se = sSum[r];
    float lse = __logf(se);
    float gscale = qlog + stab - HLM_F;
    float gln = __logf(fmaxf(goc - gqk, 1e-24f)) + gscale;
    float mx2 = fmaxf(lse, gln), mn2 = fminf(lse, gln);
    float lognorm = mx2 + log1pf(__expf(mn2 - mx2));
    sGps[r] = __expf(gscale - lognorm);
    sRin[r] = 1.f / se;
  }
  __syncthreads();

  float gpr[4], rin[4];
#pragma unroll
  for (int reg = 0; reg < 4; ++reg) {
    int rl = wv * 16 + g * 4 + reg;
    gpr[reg] = sGps[rl];
    rin[reg] = sRin[rl];
  }
#pragma unroll
  for (int nt = 0; nt < 12; ++nt) {
    int j = nt * 16 + ln;
#pragma unroll
    for (int reg = 0; reg < 4; ++reg) {
      int rl = wv * 16 + g * 4 + reg;
      bool causal = (j >= 128) && (j <= 128 + rl);
      bool bprev = (j >= rl) && (j < 128) && (j >= jmin);
      float coef = causal ? (1.f - SCALE_F) * gpr[reg] : (bprev ? -SCALE_F * gpr[reg] : 0.f);
      float wgt = eF[nt][reg] * rin[reg] + coef * pF[nt][reg];
      float wn = __shfl_xor(wgt, 1);
      if ((ln & 1) == 0) {
        *(unsigned*)(sKW + (rl * 384 + ((j * 2) ^ ((rl & 7) << 4)))) = pk2(wgt, wn);
      }
    }
  }
  __syncthreads();

  for (int w = t; w < 1024; w += 256) {
    int d = w >> 4, mp = w & 15;
    int m0 = 2 * mp, m1 = m0 + 1;
    float a = (m0 < 24) ? sPfx[m0 * 64 + d] : 0.f;
    float bb = (m1 < 24) ? sPfx[m1 * 64 + d] : 0.f;
    *(unsigned*)(sKp + (d * 64 + ((mp * 4) ^ ((d & 3) << 4)))) = pk2(a, bb);
  }

  f32x4 oF[4];
#pragma unroll
  for (int dt = 0; dt < 4; ++dt) { f32x4 z = {0.f, 0.f, 0.f, 0.f}; oF[dt] = z; }
  for (int vt3 = 0; vt3 < 3; ++vt3) {
    int lt = b - 2 + vt3; lt = lt < 0 ? 0 : lt;
    for (int w = t; w < 512; w += 256) {
      *(uint4*)(sQV + w * 16) = *(const uint4*)(vtw + ((size_t)h * NCH + lt) * 2048 + w * 4);
    }
    __syncthreads();
#pragma unroll
    for (int ks = 0; ks < 2; ++ks) {
      short8v aw = *(const short8v*)(sKW + (rA * 384 + ((vt3 * 128 + ks * 64 + g * 16) ^ ((rA & 7) << 4))));
#pragma unroll
      for (int dt = 0; dt < 4; ++dt) {
        int rB = dt * 16 + ln;
        short8v bv = *(const short8v*)(sQV + (rB * 128 + ((ks * 64 + g * 16) ^ ((rB & 7) << 4))));
        oF[dt] = __builtin_amdgcn_mfma_f32_16x16x32_bf16(aw, bv, oF[dt], 0, 0, 0);
      }
    }
    __syncthreads();
  }

  short8v aq = *(const short8v*)(sQp + (rA * 64 + ((g * 16) ^ ((rA & 3) << 4))));
  f32x4 ogF[4];
#pragma unroll
  for (int dt = 0; dt < 4; ++dt) {
    int rB = dt * 16 + ln;
    short8v bg = *(const short8v*)(sKp + (rB * 64 + ((g * 16) ^ ((rB & 3) << 4))));
    f32x4 z = {0.f, 0.f, 0.f, 0.f};
    ogF[dt] = __builtin_amdgcn_mfma_f32_16x16x32_bf16(aq, bg, z, 0, 0, 0);
  }

#pragma unroll
  for (int dt = 0; dt < 4; ++dt) {
    int d = dt * 16 + ln;
#pragma unroll
    for (int reg = 0; reg < 4; ++reg) {
      int rl = wv * 16 + g * 4 + reg;
      int l = b * 64 + rl;
      out[((size_t)l * NH + h) * DH + d] = oF[dt][reg] + gpr[reg] * ogF[dt][reg];
    }
  }
}

extern "C" void kernel_launch(void* const* d_in, const int* in_sizes, int n_in,
                              void* d_out, int out_size, void* d_ws, size_t ws_size,
                              hipStream_t stream)
{
  const float* qkv = (const float*)d_in[0];
  const float* proj = (const float*)d_in[1];
  float* out = (float*)d_out;
  char* ws = (char*)d_ws;

  float* pmax    = (float*)(ws + 0);           // 2048
  unsigned* kbw  = (unsigned*)(ws + 4096);     // 4194304
  unsigned* kpw  = (unsigned*)(ws + 4198400);  // 2097152
  float* kpfx    = (float*)(ws + 6295552);     // 3145728
  float* kvs     = (float*)(ws + 9441280);     // 3145728
  unsigned* vtw  = (unsigned*)(ws + 12587008); // 4194304
  float* kdash   = (float*)(ws + 16781312);    // 3145728 (fallback only)
  float* qdash   = (float*)(ws + 19927040);    // 3145728 (fallback only)
  float* knorm   = (float*)(ws + 23072768);    // 131072  (fallback only)
  float* qnorm   = (float*)(ws + 23203840);    // 131072  (fallback only)
  unsigned* qbw  = (unsigned*)(ws + 23334912); // 4194304 (fallback only) -> ends 27529216

  void* args[] = {
      (void*)&qkv, (void*)&proj, (void*)&pmax, (void*)&kbw, (void*)&kpw,
      (void*)&kpfx, (void*)&kvs, (void*)&vtw, (void*)&out};
  hipError_t err = hipLaunchCooperativeKernel((const void*)fused_attn, dim3(NCH, NH, 1),
                                              dim3(256, 1, 1), args, 0, stream);
  if (err != hipSuccess) {
    // deterministic fallback: verified 3-kernel path (identical numerics)
    k1_feat<<<dim3(NCH, NH), 256, 0, stream>>>(qkv, proj, kdash, knorm, qdash, qnorm, pmax, kbw, qbw);
    k3_kprime<<<dim3(NCH, NH), 256, 0, stream>>>(qkv, kdash, knorm, pmax, kpw, kpfx, kvs, vtw);
    k6_attn<<<dim3(NCH, NH), 256, 0, stream>>>(kpw, kpfx, kvs, vtw, qdash, qnorm, pmax, kbw, qbw, out);
  }
}

// Round 8
// 120.585 us; speedup vs baseline: 1.7876x; 1.7876x over previous
//
#include <hip/hip_runtime.h>
#include <hip/hip_bf16.h>

#define L_SEQ 2048
#define NH 16
#define DH 64
#define NCH 32
#define SCALE_F 0.125f
#define EPS_F 1e-4f
#define DN_F 0.35355339059327373f      // sqrt(0.125)
#define HLM_F 1.5890269151739727f      // 0.5*log(24)

typedef __attribute__((ext_vector_type(8))) short short8v;   // 8 bf16 (MFMA A/B frag)
typedef __attribute__((ext_vector_type(4))) float f32x4;     // MFMA C/D frag

// round-to-nearest-even f32 -> bf16
__device__ __forceinline__ unsigned short f2bf(float x) {
  unsigned u = __float_as_uint(x);
  u += 0x7FFFu + ((u >> 16) & 1u);
  return (unsigned short)(u >> 16);
}
__device__ __forceinline__ unsigned pk2(float a, float b) {
  return (unsigned)f2bf(a) | ((unsigned)f2bf(b) << 16);
}
__device__ __forceinline__ float stab_from_pmax(const float* __restrict__ pmax, int h, int t) {
  float v = pmax[h * 32 + (t & 31)];
  v = fmaxf(v, __shfl_xor(v, 1));  v = fmaxf(v, __shfl_xor(v, 2));
  v = fmaxf(v, __shfl_xor(v, 4));  v = fmaxf(v, __shfl_xor(v, 8));
  v = fmaxf(v, __shfl_xor(v, 16));
  return v;
}

// ---------------- K1: features. Grid (32,16,2): z=0 K-pass (kdash/knorm/kbw/pmax),
//                   z=1 Q-pass (qdash/qnorm/qbw). Bit-identical to the fused loop version.
__global__ __launch_bounds__(256) void k1_feat(
    const float* __restrict__ qkv, const float* __restrict__ proj,
    float* __restrict__ kdash, float* __restrict__ knorm,
    float* __restrict__ qdash, float* __restrict__ qnorm,
    float* __restrict__ pmax, unsigned* __restrict__ kbw, unsigned* __restrict__ qbw)
{
  __shared__ __attribute__((aligned(16))) float sP[24][68];
  __shared__ __attribute__((aligned(16))) float sX[64][68];
  __shared__ float sRed[256];
  const int c = blockIdx.x, h = blockIdx.y, qk = blockIdx.z, t = threadIdx.x;
  const int slot = qk ? 0 : 1;          // z=0 -> K (slot1), z=1 -> Q (slot0)
  for (int i = t; i < 24 * 64; i += 256) sP[i >> 6][i & 63] = proj[i];
  for (int i = t; i < 1024; i += 256) {
    int rr = i >> 4, d4 = (i & 15) * 4;
    int l = c * 64 + rr;
    *(float4*)&sX[rr][d4] = *(const float4*)(qkv + (((size_t)l * 3 + slot) * NH + h) * DH + d4);
  }
  __syncthreads();
  // bf16 pre-swizzled emit
  unsigned* dstw = qk ? qbw : kbw;
  for (int w = t; w < 2048; w += 256) {
    int rr = w >> 5, wo = w & 31;
    int l = c * 64 + rr;
    float2 xv = *(const float2*)&sX[rr][2 * wo];
    dstw[((size_t)h * L_SEQ + l) * 32 + (wo ^ ((rr & 7) << 2))] = pk2(xv.x, xv.y);
  }
  const int r = t >> 2, mg = t & 3;
  float acc[6] = {0.f, 0.f, 0.f, 0.f, 0.f, 0.f};
  float sq = 0.f;
  for (int d4 = 0; d4 < 16; ++d4) {
    float4 xv = *(const float4*)&sX[r][d4 * 4];
    sq += xv.x * xv.x; sq += xv.y * xv.y; sq += xv.z * xv.z; sq += xv.w * xv.w;
#pragma unroll
    for (int i = 0; i < 6; ++i) {
      float4 pv = *(const float4*)&sP[mg * 6 + i][d4 * 4];
      acc[i] += xv.x * pv.x; acc[i] += xv.y * pv.y;
      acc[i] += xv.z * pv.z; acc[i] += xv.w * pv.w;
    }
  }
  int l = c * 64 + r;
  float* dsh = qk ? qdash : kdash;
  float lmax = -1e30f;
#pragma unroll
  for (int i = 0; i < 6; ++i) {
    float v = acc[i] * DN_F;
    dsh[((size_t)h * L_SEQ + l) * 24 + mg * 6 + i] = v;
    lmax = fmaxf(lmax, v);
  }
  if (mg == 0) (qk ? qnorm : knorm)[h * L_SEQ + l] = 0.5f * SCALE_F * sq;
  if (qk == 0) {
    sRed[t] = lmax;
    __syncthreads();
#pragma unroll
    for (int s = 128; s > 0; s >>= 1) {
      if (t < s) sRed[t] = fmaxf(sRed[t], sRed[t + s]);
      __syncthreads();
    }
    if (t == 0) pmax[h * 32 + c] = sRed[0];
  }
}

// ---------------- K3: k' (bf16 padded 32, pre-swizzled), kpfx, kvs, V^T pre-swizzled
__global__ __launch_bounds__(256) void k3_kprime(
    const float* __restrict__ qkv, const float* __restrict__ kdash,
    const float* __restrict__ knorm, const float* __restrict__ pmax,
    unsigned* __restrict__ kpw, float* __restrict__ kpfx, float* __restrict__ kvs,
    unsigned* __restrict__ vtw)
{
  __shared__ float sKp[64][25];
  __shared__ __attribute__((aligned(16))) float sV[64][68];
  const int c = blockIdx.x, h = blockIdx.y, t = threadIdx.x;
  const float stab = stab_from_pmax(pmax, h, t);
  for (int i = t; i < 1024; i += 256) {
    int rr = i >> 4, d4 = (i & 15) * 4;
    int l = c * 64 + rr;
    *(float4*)&sV[rr][d4] = *(const float4*)(qkv + (((size_t)l * 3 + 2) * NH + h) * DH + d4);
  }
  for (int i = t; i < 1536; i += 256) {
    int r = i / 24, m = i % 24;
    int l = c * 64 + r;
    sKp[r][m] = __expf(kdash[((size_t)h * L_SEQ + l) * 24 + m] - knorm[h * L_SEQ + l] - stab) + EPS_F;
  }
  __syncthreads();
  for (int w = t; w < 1024; w += 256) {
    int r = w >> 4, wo = w & 15;
    int l = c * 64 + r;
    float a = (wo < 12) ? sKp[r][2 * wo] : 0.f;
    float bb = (wo < 12) ? sKp[r][2 * wo + 1] : 0.f;
    kpw[((size_t)h * L_SEQ + l) * 16 + (wo ^ ((r & 3) << 2))] = pk2(a, bb);
  }
  for (int w = t; w < 2048; w += 256) {
    int d = w >> 5, jp = w & 31;
    vtw[((size_t)h * NCH + c) * 2048 + d * 32 + (jp ^ ((d & 7) << 2))] = pk2(sV[2 * jp][d], sV[2 * jp + 1][d]);
  }
  if (t < 192) {
    const int m = t % 24, dO = (t / 24) * 8;
    float a0x = 0.f, a0y = 0.f, a0z = 0.f, a0w = 0.f;
    float a1x = 0.f, a1y = 0.f, a1z = 0.f, a1w = 0.f;
    for (int r2 = 0; r2 < 64; ++r2) {
      float kp = sKp[r2][m];
      float4 v0 = *(const float4*)&sV[r2][dO];
      float4 v1 = *(const float4*)&sV[r2][dO + 4];
      a0x += kp * v0.x; a0y += kp * v0.y; a0z += kp * v0.z; a0w += kp * v0.w;
      a1x += kp * v1.x; a1y += kp * v1.y; a1z += kp * v1.z; a1w += kp * v1.w;
    }
    float* dst = kvs + ((size_t)h * NCH + c) * 1536 + m * 64 + dO;
    float4 o0 = {a0x, a0y, a0z, a0w};
    float4 o1 = {a1x, a1y, a1z, a1w};
    *(float4*)dst = o0;
    *(float4*)(dst + 4) = o1;
  }
  if (t < 24) {
    float run = 0.f;
    for (int r2 = 0; r2 < 64; ++r2) {
      run += sKp[r2][t];
      kpfx[((size_t)h * L_SEQ + c * 64 + r2) * 24 + t] = run;
    }
  }
}

// ---------------- K6: fused banded + performer attention, one block per (h, 64-row chunk)
__global__ __launch_bounds__(256, 2) void k6_attn(
    const unsigned* __restrict__ kpw, const float* __restrict__ kpfx,
    const float* __restrict__ kvs, const unsigned* __restrict__ vtw,
    const float* __restrict__ qdash, const float* __restrict__ qnorm,
    const float* __restrict__ pmax, const unsigned* __restrict__ kbw,
    const unsigned* __restrict__ qbw, float* __restrict__ out)
{
  __shared__ __attribute__((aligned(16))) char lds[56160];
  char* sKW = lds;                       // [192][64]b16 K; later W [64][192]b16
  char* sKp = lds + 24576;               // [192][32]b16 k'; later KVexcl^T
  char* sQV = lds + 36864;               // [64][64]b16 Q; later V^T tile
  char* sQp = lds + 45056;               // [64][32]b16 q'
  float* sSum = (float*)(lds + 49152);   // 64
  float* sGps = sSum + 64;
  float* sRin = sGps + 64;
  float* sKcx = (float*)(lds + 49920);   // 24 used
  float* sPfx = (float*)(lds + 50016);   // [1536] f32 KVexcl -> ends 56160

  const int b = blockIdx.x, h = blockIdx.y, t = threadIdx.x;
  const int wv = t >> 6, lane = t & 63, g = lane >> 4, ln = lane & 15;
  const int keybase = b * 64 - 128;
  const int jmin = (b >= 2) ? 0 : (128 - 64 * b);
  const int rA = wv * 16 + ln;

  for (int w = t; w < 1536; w += 256) {
    int r = w >> 3, q4 = w & 7;
    int l = keybase + r; l = l < 0 ? 0 : l;
    *(uint4*)(sKW + r * 128 + q4 * 16) = *(const uint4*)(kbw + ((size_t)h * L_SEQ + l) * 32 + q4 * 4);
  }
  for (int w = t; w < 512; w += 256) {
    int r = w >> 3, q4 = w & 7;
    int l = b * 64 + r;
    *(uint4*)(sQV + r * 128 + q4 * 16) = *(const uint4*)(qbw + ((size_t)h * L_SEQ + l) * 32 + q4 * 4);
  }
  for (int w = t; w < 768; w += 256) {
    int r = w >> 2, q4 = w & 3;
    int l = keybase + r; l = l < 0 ? 0 : l;
    *(uint4*)(sKp + r * 64 + q4 * 16) = *(const uint4*)(kpw + ((size_t)h * L_SEQ + l) * 16 + q4 * 4);
  }
  const float stab = stab_from_pmax(pmax, h, t);
  // exclusive chunk-prefix of kvs (unroll 4: 24 loads in flight, same add order)
  {
    float accp[6] = {0.f, 0.f, 0.f, 0.f, 0.f, 0.f};
    const float* srcb = kvs + (size_t)h * NCH * 1536 + t;
    int bp = 0;
    for (; bp + 4 <= b; bp += 4) {
      float v0[6], v1[6], v2[6], v3[6];
#pragma unroll
      for (int j = 0; j < 6; ++j) v0[j] = srcb[(size_t)(bp + 0) * 1536 + j * 256];
#pragma unroll
      for (int j = 0; j < 6; ++j) v1[j] = srcb[(size_t)(bp + 1) * 1536 + j * 256];
#pragma unroll
      for (int j = 0; j < 6; ++j) v2[j] = srcb[(size_t)(bp + 2) * 1536 + j * 256];
#pragma unroll
      for (int j = 0; j < 6; ++j) v3[j] = srcb[(size_t)(bp + 3) * 1536 + j * 256];
#pragma unroll
      for (int j = 0; j < 6; ++j) {
        accp[j] += v0[j]; accp[j] += v1[j]; accp[j] += v2[j]; accp[j] += v3[j];
      }
    }
    for (; bp < b; ++bp) {
#pragma unroll
      for (int j = 0; j < 6; ++j) accp[j] += srcb[(size_t)bp * 1536 + j * 256];
    }
#pragma unroll
    for (int j = 0; j < 6; ++j) sPfx[t + j * 256] = accp[j];
  }
  if (t < 24) {
    float runk = 0.f;
    for (int bp = 0; bp < b; ++bp)
      runk += kpfx[((size_t)h * L_SEQ + bp * 64 + 63) * 24 + t];
    sKcx[t] = runk;
  }
  // q' per row: registers (stats) + bf16 frag copy to LDS
  float qlog = 0.f;
  float qpv[24];
  if (t < 64) {
    int r = t, l = b * 64 + r;
    const float* qdp = qdash + ((size_t)h * L_SEQ + l) * 24;
    float qd[24], mx = -1e30f;
#pragma unroll
    for (int m = 0; m < 24; ++m) { qd[m] = qdp[m]; mx = fmaxf(mx, qd[m]); }
#pragma unroll
    for (int m = 0; m < 24; ++m) qpv[m] = __expf(qd[m] - mx) + EPS_F;
    qlog = mx - qnorm[h * L_SEQ + l] - HLM_F;
#pragma unroll
    for (int wo = 0; wo < 16; ++wo) {
      float a = (wo < 12) ? qpv[2 * wo] : 0.f;
      float bb = (wo < 12) ? qpv[2 * wo + 1] : 0.f;
      *(unsigned*)(sQp + (r * 64 + (((wo * 4)) ^ ((r & 3) << 4)))) = pk2(a, bb);
    }
  }
  __syncthreads();

  // ---- S = Q K^T (masked exp), wave-local row sums ----
  float eF[12][4];
  float rs[4] = {0.f, 0.f, 0.f, 0.f};
  short8v aS0 = *(const short8v*)(sQV + (rA * 128 + ((g * 16) ^ ((rA & 7) << 4))));
  short8v aS1 = *(const short8v*)(sQV + (rA * 128 + ((64 + g * 16) ^ ((rA & 7) << 4))));
#pragma unroll
  for (int nt = 0; nt < 12; ++nt) {
    int rB = nt * 16 + ln;
    short8v b0 = *(const short8v*)(sKW + (rB * 128 + ((g * 16) ^ ((rB & 7) << 4))));
    short8v b1 = *(const short8v*)(sKW + (rB * 128 + ((64 + g * 16) ^ ((rB & 7) << 4))));
    f32x4 acc = {0.f, 0.f, 0.f, 0.f};
    acc = __builtin_amdgcn_mfma_f32_16x16x32_bf16(aS0, b0, acc, 0, 0, 0);
    acc = __builtin_amdgcn_mfma_f32_16x16x32_bf16(aS1, b1, acc, 0, 0, 0);
    int j = nt * 16 + ln;
#pragma unroll
    for (int reg = 0; reg < 4; ++reg) {
      int rl = wv * 16 + g * 4 + reg;
      float e = 0.f;
      if (j >= rl && j <= rl + 128 && j >= jmin) e = __expf(SCALE_F * acc[reg]);
      eF[nt][reg] = e;
      rs[reg] += e;
    }
  }
#pragma unroll
  for (int reg = 0; reg < 4; ++reg) {
    float v = rs[reg];
    v += __shfl_xor(v, 1); v += __shfl_xor(v, 2);
    v += __shfl_xor(v, 4); v += __shfl_xor(v, 8);
    if (ln == 0) sSum[wv * 16 + g * 4 + reg] = v;
  }

  // ---- P = q' k'^T ----
  float pF[12][4];
  short8v aP = *(const short8v*)(sQp + (rA * 64 + ((g * 16) ^ ((rA & 3) << 4))));
#pragma unroll
  for (int nt = 0; nt < 12; ++nt) {
    int rB = nt * 16 + ln;
    short8v bp = *(const short8v*)(sKp + (rB * 64 + ((g * 16) ^ ((rB & 3) << 4))));
    f32x4 acc = {0.f, 0.f, 0.f, 0.f};
    acc = __builtin_amdgcn_mfma_f32_16x16x32_bf16(aP, bp, acc, 0, 0, 0);
#pragma unroll
    for (int reg = 0; reg < 4; ++reg) pF[nt][reg] = acc[reg];
  }
  __syncthreads();

  // ---- per-row stats (qpv in registers) ----
  if (t < 64) {
    int r = t, l = b * 64 + r;
    const float* kfc = kpfx + ((size_t)h * L_SEQ + l) * 24;
    int b1i = (b >= 1) ? b - 1 : 0;
    int b2i = (b >= 2) ? b - 2 : 0;
    int rm1 = (r >= 1) ? r - 1 : 0;
    const float* T1p = kpfx + ((size_t)h * L_SEQ + b1i * 64 + 63) * 24;
    const float* T2p = kpfx + ((size_t)h * L_SEQ + b2i * 64 + 63) * 24;
    const float* S2p = kpfx + ((size_t)h * L_SEQ + b2i * 64 + rm1) * 24;
    float f1 = (b >= 1) ? 1.f : 0.f;
    float f2 = (b >= 2) ? 1.f : 0.f;
    float fr = (b >= 2 && r >= 1) ? 1.f : 0.f;
    float psc = 0.f, kcs = 0.f, bnd = 0.f;
#pragma unroll
    for (int m = 0; m < 24; ++m) {
      float qp = qpv[m];
      float kc = kfc[m];
      psc += qp * kc;
      kcs += qp * sKcx[m];
      bnd += qp * (kc + f1 * T1p[m] + f2 * T2p[m] - fr * S2p[m]);
    }
    float goc = kcs + psc;
    float gqk = SCALE_F * bnd;
    float se = sSum[r];
    float lse = __logf(se);
    float gscale = qlog + stab - HLM_F;
    float gln = __logf(fmaxf(goc - gqk, 1e-24f)) + gscale;
    float mx2 = fmaxf(lse, gln), mn2 = fminf(lse, gln);
    float lognorm = mx2 + log1pf(__expf(mn2 - mx2));
    sGps[r] = __expf(gscale - lognorm);
    sRin[r] = 1.f / se;
  }
  __syncthreads();

  // ---- form W (bf16) into old K region ----
  float gpr[4], rin[4];
#pragma unroll
  for (int reg = 0; reg < 4; ++reg) {
    int rl = wv * 16 + g * 4 + reg;
    gpr[reg] = sGps[rl];
    rin[reg] = sRin[rl];
  }
#pragma unroll
  for (int nt = 0; nt < 12; ++nt) {
    int j = nt * 16 + ln;
#pragma unroll
    for (int reg = 0; reg < 4; ++reg) {
      int rl = wv * 16 + g * 4 + reg;
      bool causal = (j >= 128) && (j <= 128 + rl);
      bool bprev = (j >= rl) && (j < 128) && (j >= jmin);
      float coef = causal ? (1.f - SCALE_F) * gpr[reg] : (bprev ? -SCALE_F * gpr[reg] : 0.f);
      float wgt = eF[nt][reg] * rin[reg] + coef * pF[nt][reg];
      float wn = __shfl_xor(wgt, 1);
      if ((ln & 1) == 0) {
        *(unsigned*)(sKW + (rl * 384 + ((j * 2) ^ ((rl & 7) << 4)))) = pk2(wgt, wn);
      }
    }
  }
  __syncthreads();

  // ---- pack KVexcl^T bf16 into sKp (from sPfx) ----
  for (int w = t; w < 1024; w += 256) {
    int d = w >> 4, mp = w & 15;
    int m0 = 2 * mp, m1 = m0 + 1;
    float a = (m0 < 24) ? sPfx[m0 * 64 + d] : 0.f;
    float bb = (m1 < 24) ? sPfx[m1 * 64 + d] : 0.f;
    *(unsigned*)(sKp + (d * 64 + ((mp * 4) ^ ((d & 3) << 4)))) = pk2(a, bb);
  }

  // ---- O1 = W * V (192-K), V^T tiles staged per 64 cols ----
  f32x4 oF[4];
#pragma unroll
  for (int dt = 0; dt < 4; ++dt) { f32x4 z = {0.f, 0.f, 0.f, 0.f}; oF[dt] = z; }
  for (int vt3 = 0; vt3 < 3; ++vt3) {
    int lt = b - 2 + vt3; lt = lt < 0 ? 0 : lt;
    for (int w = t; w < 512; w += 256) {
      *(uint4*)(sQV + w * 16) = *(const uint4*)(vtw + ((size_t)h * NCH + lt) * 2048 + w * 4);
    }
    __syncthreads();
#pragma unroll
    for (int ks = 0; ks < 2; ++ks) {
      short8v aw = *(const short8v*)(sKW + (rA * 384 + ((vt3 * 128 + ks * 64 + g * 16) ^ ((rA & 7) << 4))));
#pragma unroll
      for (int dt = 0; dt < 4; ++dt) {
        int rB = dt * 16 + ln;
        short8v bv = *(const short8v*)(sQV + (rB * 128 + ((ks * 64 + g * 16) ^ ((rB & 7) << 4))));
        oF[dt] = __builtin_amdgcn_mfma_f32_16x16x32_bf16(aw, bv, oF[dt], 0, 0, 0);
      }
    }
    __syncthreads();
  }

  // ---- Og = q' * KVexcl ----
  short8v aq = *(const short8v*)(sQp + (rA * 64 + ((g * 16) ^ ((rA & 3) << 4))));
  f32x4 ogF[4];
#pragma unroll
  for (int dt = 0; dt < 4; ++dt) {
    int rB = dt * 16 + ln;
    short8v bg = *(const short8v*)(sKp + (rB * 64 + ((g * 16) ^ ((rB & 3) << 4))));
    f32x4 z = {0.f, 0.f, 0.f, 0.f};
    ogF[dt] = __builtin_amdgcn_mfma_f32_16x16x32_bf16(aq, bg, z, 0, 0, 0);
  }

  // ---- epilogue ----
#pragma unroll
  for (int dt = 0; dt < 4; ++dt) {
    int d = dt * 16 + ln;
#pragma unroll
    for (int reg = 0; reg < 4; ++reg) {
      int rl = wv * 16 + g * 4 + reg;
      int l = b * 64 + rl;
      out[((size_t)l * NH + h) * DH + d] = oF[dt][reg] + gpr[reg] * ogF[dt][reg];
    }
  }
}

extern "C" void kernel_launch(void* const* d_in, const int* in_sizes, int n_in,
                              void* d_out, int out_size, void* d_ws, size_t ws_size,
                              hipStream_t stream)
{
  const float* qkv = (const float*)d_in[0];
  const float* proj = (const float*)d_in[1];
  float* out = (float*)d_out;
  char* ws = (char*)d_ws;

  float* kdash   = (float*)(ws + 0);           // 3145728
  float* qdash   = (float*)(ws + 3145728);     // 3145728
  float* knorm   = (float*)(ws + 6291456);     // 131072
  float* qnorm   = (float*)(ws + 6422528);     // 131072
  float* pmax    = (float*)(ws + 6553600);     // 2048
  unsigned* kbw  = (unsigned*)(ws + 6555648);  // 4194304
  unsigned* qbw  = (unsigned*)(ws + 10749952); // 4194304
  unsigned* kpw  = (unsigned*)(ws + 14944256); // 2097152
  float* kpfx    = (float*)(ws + 17041408);    // 3145728
  unsigned* vtw  = (unsigned*)(ws + 20187136); // 4194304
  float* kvs     = (float*)(ws + 24381440);    // 3145728 (ends at 27527168)

  k1_feat<<<dim3(NCH, NH, 2), 256, 0, stream>>>(qkv, proj, kdash, knorm, qdash, qnorm, pmax, kbw, qbw);
  k3_kprime<<<dim3(NCH, NH), 256, 0, stream>>>(qkv, kdash, knorm, pmax, kpw, kpfx, kvs, vtw);
  k6_attn<<<dim3(NCH, NH), 256, 0, stream>>>(kpw, kpfx, kvs, vtw, qdash, qnorm, pmax, kbw, qbw, out);
}

// Round 9
// 119.970 us; speedup vs baseline: 1.7968x; 1.0051x over previous
//
#include <hip/hip_runtime.h>
#include <hip/hip_bf16.h>

#define L_SEQ 2048
#define NH 16
#define DH 64
#define NCH 32
#define SCALE_F 0.125f
#define EPS_F 1e-4f
#define DN_F 0.35355339059327373f      // sqrt(0.125)
#define HLM_F 1.5890269151739727f      // 0.5*log(24)

typedef __attribute__((ext_vector_type(8))) short short8v;   // 8 bf16 (MFMA A/B frag)
typedef __attribute__((ext_vector_type(4))) float f32x4;     // MFMA C/D frag

// round-to-nearest-even f32 -> bf16
__device__ __forceinline__ unsigned short f2bf(float x) {
  unsigned u = __float_as_uint(x);
  u += 0x7FFFu + ((u >> 16) & 1u);
  return (unsigned short)(u >> 16);
}
__device__ __forceinline__ unsigned pk2(float a, float b) {
  return (unsigned)f2bf(a) | ((unsigned)f2bf(b) << 16);
}
__device__ __forceinline__ float stab_from_pmax(const float* __restrict__ pmax, int h, int t) {
  float v = pmax[h * 32 + (t & 31)];
  v = fmaxf(v, __shfl_xor(v, 1));  v = fmaxf(v, __shfl_xor(v, 2));
  v = fmaxf(v, __shfl_xor(v, 4));  v = fmaxf(v, __shfl_xor(v, 8));
  v = fmaxf(v, __shfl_xor(v, 16));
  return v;
}

// ---------------- K1: features. Grid (32,16,2): z=0 K-pass (kdash/knorm/kbw/pmax),
//                   z=1 Q-pass (qdash/qnorm/qbw).
__global__ __launch_bounds__(256) void k1_feat(
    const float* __restrict__ qkv, const float* __restrict__ proj,
    float* __restrict__ kdash, float* __restrict__ knorm,
    float* __restrict__ qdash, float* __restrict__ qnorm,
    float* __restrict__ pmax, unsigned* __restrict__ kbw, unsigned* __restrict__ qbw)
{
  __shared__ __attribute__((aligned(16))) float sP[24][68];
  __shared__ __attribute__((aligned(16))) float sX[64][68];
  __shared__ float sRed[256];
  const int c = blockIdx.x, h = blockIdx.y, qk = blockIdx.z, t = threadIdx.x;
  const int slot = qk ? 0 : 1;          // z=0 -> K (slot1), z=1 -> Q (slot0)
  for (int i = t; i < 24 * 64; i += 256) sP[i >> 6][i & 63] = proj[i];
  for (int i = t; i < 1024; i += 256) {
    int rr = i >> 4, d4 = (i & 15) * 4;
    int l = c * 64 + rr;
    *(float4*)&sX[rr][d4] = *(const float4*)(qkv + (((size_t)l * 3 + slot) * NH + h) * DH + d4);
  }
  __syncthreads();
  // bf16 pre-swizzled emit
  unsigned* dstw = qk ? qbw : kbw;
  for (int w = t; w < 2048; w += 256) {
    int rr = w >> 5, wo = w & 31;
    int l = c * 64 + rr;
    float2 xv = *(const float2*)&sX[rr][2 * wo];
    dstw[((size_t)h * L_SEQ + l) * 32 + (wo ^ ((rr & 7) << 2))] = pk2(xv.x, xv.y);
  }
  const int r = t >> 2, mg = t & 3;
  float acc[6] = {0.f, 0.f, 0.f, 0.f, 0.f, 0.f};
  float sq = 0.f;
  for (int d4 = 0; d4 < 16; ++d4) {
    float4 xv = *(const float4*)&sX[r][d4 * 4];
    sq += xv.x * xv.x; sq += xv.y * xv.y; sq += xv.z * xv.z; sq += xv.w * xv.w;
#pragma unroll
    for (int i = 0; i < 6; ++i) {
      float4 pv = *(const float4*)&sP[mg * 6 + i][d4 * 4];
      acc[i] += xv.x * pv.x; acc[i] += xv.y * pv.y;
      acc[i] += xv.z * pv.z; acc[i] += xv.w * pv.w;
    }
  }
  int l = c * 64 + r;
  float* dsh = qk ? qdash : kdash;
  float lmax = -1e30f;
#pragma unroll
  for (int i = 0; i < 6; ++i) {
    float v = acc[i] * DN_F;
    dsh[((size_t)h * L_SEQ + l) * 24 + mg * 6 + i] = v;
    lmax = fmaxf(lmax, v);
  }
  if (mg == 0) (qk ? qnorm : knorm)[h * L_SEQ + l] = 0.5f * SCALE_F * sq;
  if (qk == 0) {
    sRed[t] = lmax;
    __syncthreads();
#pragma unroll
    for (int s = 128; s > 0; s >>= 1) {
      if (t < s) sRed[t] = fmaxf(sRed[t], sRed[t + s]);
      __syncthreads();
    }
    if (t == 0) pmax[h * 32 + c] = sRed[0];
  }
}

// ---------------- K3: k' (bf16 padded 32, pre-swizzled), kpfx, kvs, V^T pre-swizzled.
//                   kpfx scan moved to wave 3 (t in [192,216)) to run concurrently with kvs.
__global__ __launch_bounds__(256) void k3_kprime(
    const float* __restrict__ qkv, const float* __restrict__ kdash,
    const float* __restrict__ knorm, const float* __restrict__ pmax,
    unsigned* __restrict__ kpw, float* __restrict__ kpfx, float* __restrict__ kvs,
    unsigned* __restrict__ vtw)
{
  __shared__ float sKp[64][25];
  __shared__ __attribute__((aligned(16))) float sV[64][68];
  const int c = blockIdx.x, h = blockIdx.y, t = threadIdx.x;
  const float stab = stab_from_pmax(pmax, h, t);
  for (int i = t; i < 1024; i += 256) {
    int rr = i >> 4, d4 = (i & 15) * 4;
    int l = c * 64 + rr;
    *(float4*)&sV[rr][d4] = *(const float4*)(qkv + (((size_t)l * 3 + 2) * NH + h) * DH + d4);
  }
  for (int i = t; i < 1536; i += 256) {
    int r = i / 24, m = i % 24;
    int l = c * 64 + r;
    sKp[r][m] = __expf(kdash[((size_t)h * L_SEQ + l) * 24 + m] - knorm[h * L_SEQ + l] - stab) + EPS_F;
  }
  __syncthreads();
  for (int w = t; w < 1024; w += 256) {
    int r = w >> 4, wo = w & 15;
    int l = c * 64 + r;
    float a = (wo < 12) ? sKp[r][2 * wo] : 0.f;
    float bb = (wo < 12) ? sKp[r][2 * wo + 1] : 0.f;
    kpw[((size_t)h * L_SEQ + l) * 16 + (wo ^ ((r & 3) << 2))] = pk2(a, bb);
  }
  for (int w = t; w < 2048; w += 256) {
    int d = w >> 5, jp = w & 31;
    vtw[((size_t)h * NCH + c) * 2048 + d * 32 + (jp ^ ((d & 7) << 2))] = pk2(sV[2 * jp][d], sV[2 * jp + 1][d]);
  }
  if (t < 192) {
    const int m = t % 24, dO = (t / 24) * 8;
    float a0x = 0.f, a0y = 0.f, a0z = 0.f, a0w = 0.f;
    float a1x = 0.f, a1y = 0.f, a1z = 0.f, a1w = 0.f;
    for (int r2 = 0; r2 < 64; ++r2) {
      float kp = sKp[r2][m];
      float4 v0 = *(const float4*)&sV[r2][dO];
      float4 v1 = *(const float4*)&sV[r2][dO + 4];
      a0x += kp * v0.x; a0y += kp * v0.y; a0z += kp * v0.z; a0w += kp * v0.w;
      a1x += kp * v1.x; a1y += kp * v1.y; a1z += kp * v1.z; a1w += kp * v1.w;
    }
    float* dst = kvs + ((size_t)h * NCH + c) * 1536 + m * 64 + dO;
    float4 o0 = {a0x, a0y, a0z, a0w};
    float4 o1 = {a1x, a1y, a1z, a1w};
    *(float4*)dst = o0;
    *(float4*)(dst + 4) = o1;
  } else if (t < 216) {
    const int m = t - 192;
    float run = 0.f;
    for (int r2 = 0; r2 < 64; ++r2) {
      run += sKp[r2][m];
      kpfx[((size_t)h * L_SEQ + c * 64 + r2) * 24 + m] = run;
    }
  }
}

// ---------------- K6: fused banded + performer attention, one block per (h, 64-row chunk).
// All V^T tiles staged upfront (24KB); WV loop is barrier-free.
__global__ __launch_bounds__(256, 2) void k6_attn(
    const unsigned* __restrict__ kpw, const float* __restrict__ kpfx,
    const float* __restrict__ kvs, const unsigned* __restrict__ vtw,
    const float* __restrict__ qdash, const float* __restrict__ qnorm,
    const float* __restrict__ pmax, const unsigned* __restrict__ kbw,
    const unsigned* __restrict__ qbw, float* __restrict__ out)
{
  __shared__ __attribute__((aligned(16))) char lds[80736];
  char* sKW = lds;                       // 24576: K [192][128B]; later W [64][384B]
  char* sKp = lds + 24576;               // 12288: k' [192][64B]; later KVexcl^T [64][64B]
  char* sV  = lds + 36864;               // 24576: V^T tiles [3][64][128B] (persistent)
  char* sQ  = lds + 61440;               // 8192:  Q [64][128B]
  char* sQp = lds + 69632;               // 4096:  q' [64][64B]
  float* sSum = (float*)(lds + 73728);   // 64
  float* sGps = sSum + 64;
  float* sRin = sGps + 64;               // ends 74496
  float* sKcx = (float*)(lds + 74496);   // 24 used
  float* sPfx = (float*)(lds + 74592);   // [1536] f32 KVexcl -> ends 80736

  const int b = blockIdx.x, h = blockIdx.y, t = threadIdx.x;
  const int wv = t >> 6, lane = t & 63, g = lane >> 4, ln = lane & 15;
  const int keybase = b * 64 - 128;
  const int jmin = (b >= 2) ? 0 : (128 - 64 * b);
  const int rA = wv * 16 + ln;

  // ---- stage everything upfront (17 independent uint4 loads/thread) ----
  for (int w = t; w < 1536; w += 256) {          // K 192 rows
    int r = w >> 3, q4 = w & 7;
    int l = keybase + r; l = l < 0 ? 0 : l;
    *(uint4*)(sKW + r * 128 + q4 * 16) = *(const uint4*)(kbw + ((size_t)h * L_SEQ + l) * 32 + q4 * 4);
  }
  for (int w = t; w < 512; w += 256) {           // Q 64 rows
    int r = w >> 3, q4 = w & 7;
    int l = b * 64 + r;
    *(uint4*)(sQ + r * 128 + q4 * 16) = *(const uint4*)(qbw + ((size_t)h * L_SEQ + l) * 32 + q4 * 4);
  }
  for (int w = t; w < 768; w += 256) {           // k' 192 rows
    int r = w >> 2, q4 = w & 3;
    int l = keybase + r; l = l < 0 ? 0 : l;
    *(uint4*)(sKp + r * 64 + q4 * 16) = *(const uint4*)(kpw + ((size_t)h * L_SEQ + l) * 16 + q4 * 4);
  }
  for (int w = t; w < 1536; w += 256) {          // V^T 3 tiles
    int vt = w >> 9, idx = w & 511;
    int lt = b - 2 + vt; lt = lt < 0 ? 0 : lt;
    *(uint4*)(sV + vt * 8192 + idx * 16) = *(const uint4*)(vtw + ((size_t)h * NCH + lt) * 2048 + idx * 4);
  }
  const float stab = stab_from_pmax(pmax, h, t);
  // exclusive chunk-prefix of kvs (unroll 4, same add order)
  {
    float accp[6] = {0.f, 0.f, 0.f, 0.f, 0.f, 0.f};
    const float* srcb = kvs + (size_t)h * NCH * 1536 + t;
    int bp = 0;
    for (; bp + 4 <= b; bp += 4) {
      float v0[6], v1[6], v2[6], v3[6];
#pragma unroll
      for (int j = 0; j < 6; ++j) v0[j] = srcb[(size_t)(bp + 0) * 1536 + j * 256];
#pragma unroll
      for (int j = 0; j < 6; ++j) v1[j] = srcb[(size_t)(bp + 1) * 1536 + j * 256];
#pragma unroll
      for (int j = 0; j < 6; ++j) v2[j] = srcb[(size_t)(bp + 2) * 1536 + j * 256];
#pragma unroll
      for (int j = 0; j < 6; ++j) v3[j] = srcb[(size_t)(bp + 3) * 1536 + j * 256];
#pragma unroll
      for (int j = 0; j < 6; ++j) {
        accp[j] += v0[j]; accp[j] += v1[j]; accp[j] += v2[j]; accp[j] += v3[j];
      }
    }
    for (; bp < b; ++bp) {
#pragma unroll
      for (int j = 0; j < 6; ++j) accp[j] += srcb[(size_t)bp * 1536 + j * 256];
    }
#pragma unroll
    for (int j = 0; j < 6; ++j) sPfx[t + j * 256] = accp[j];
  }
  if (t < 24) {
    float runk = 0.f;
    for (int bp = 0; bp < b; ++bp)
      runk += kpfx[((size_t)h * L_SEQ + bp * 64 + 63) * 24 + t];
    sKcx[t] = runk;
  }
  // q' per row: registers (stats) + bf16 frag copy to LDS (float4 qdash loads)
  float qlog = 0.f;
  float qpv[24];
  if (t < 64) {
    int r = t, l = b * 64 + r;
    const float* qdp = qdash + ((size_t)h * L_SEQ + l) * 24;
    float qd[24];
#pragma unroll
    for (int i = 0; i < 6; ++i) {
      float4 v = *(const float4*)(qdp + 4 * i);
      qd[4 * i] = v.x; qd[4 * i + 1] = v.y; qd[4 * i + 2] = v.z; qd[4 * i + 3] = v.w;
    }
    float mx = -1e30f;
#pragma unroll
    for (int m = 0; m < 24; ++m) mx = fmaxf(mx, qd[m]);
#pragma unroll
    for (int m = 0; m < 24; ++m) qpv[m] = __expf(qd[m] - mx) + EPS_F;
    qlog = mx - qnorm[h * L_SEQ + l] - HLM_F;
#pragma unroll
    for (int wo = 0; wo < 16; ++wo) {
      float a = (wo < 12) ? qpv[2 * wo] : 0.f;
      float bb = (wo < 12) ? qpv[2 * wo + 1] : 0.f;
      *(unsigned*)(sQp + (r * 64 + (((wo * 4)) ^ ((r & 3) << 4)))) = pk2(a, bb);
    }
  }
  __syncthreads();

  // ---- S = Q K^T (masked exp), wave-local row sums ----
  float eF[12][4];
  float rs[4] = {0.f, 0.f, 0.f, 0.f};
  short8v aS0 = *(const short8v*)(sQ + (rA * 128 + ((g * 16) ^ ((rA & 7) << 4))));
  short8v aS1 = *(const short8v*)(sQ + (rA * 128 + ((64 + g * 16) ^ ((rA & 7) << 4))));
#pragma unroll
  for (int nt = 0; nt < 12; ++nt) {
    int rB = nt * 16 + ln;
    short8v b0 = *(const short8v*)(sKW + (rB * 128 + ((g * 16) ^ ((rB & 7) << 4))));
    short8v b1 = *(const short8v*)(sKW + (rB * 128 + ((64 + g * 16) ^ ((rB & 7) << 4))));
    f32x4 acc = {0.f, 0.f, 0.f, 0.f};
    acc = __builtin_amdgcn_mfma_f32_16x16x32_bf16(aS0, b0, acc, 0, 0, 0);
    acc = __builtin_amdgcn_mfma_f32_16x16x32_bf16(aS1, b1, acc, 0, 0, 0);
    int j = nt * 16 + ln;
#pragma unroll
    for (int reg = 0; reg < 4; ++reg) {
      int rl = wv * 16 + g * 4 + reg;
      float e = 0.f;
      if (j >= rl && j <= rl + 128 && j >= jmin) e = __expf(SCALE_F * acc[reg]);
      eF[nt][reg] = e;
      rs[reg] += e;
    }
  }
#pragma unroll
  for (int reg = 0; reg < 4; ++reg) {
    float v = rs[reg];
    v += __shfl_xor(v, 1); v += __shfl_xor(v, 2);
    v += __shfl_xor(v, 4); v += __shfl_xor(v, 8);
    if (ln == 0) sSum[wv * 16 + g * 4 + reg] = v;
  }

  // ---- P = q' k'^T ----
  float pF[12][4];
  short8v aP = *(const short8v*)(sQp + (rA * 64 + ((g * 16) ^ ((rA & 3) << 4))));
#pragma unroll
  for (int nt = 0; nt < 12; ++nt) {
    int rB = nt * 16 + ln;
    short8v bp = *(const short8v*)(sKp + (rB * 64 + ((g * 16) ^ ((rB & 3) << 4))));
    f32x4 acc = {0.f, 0.f, 0.f, 0.f};
    acc = __builtin_amdgcn_mfma_f32_16x16x32_bf16(aP, bp, acc, 0, 0, 0);
#pragma unroll
    for (int reg = 0; reg < 4; ++reg) pF[nt][reg] = acc[reg];
  }
  __syncthreads();

  // ---- per-row stats (qpv in registers) ----
  if (t < 64) {
    int r = t, l = b * 64 + r;
    const float* kfc = kpfx + ((size_t)h * L_SEQ + l) * 24;
    int b1i = (b >= 1) ? b - 1 : 0;
    int b2i = (b >= 2) ? b - 2 : 0;
    int rm1 = (r >= 1) ? r - 1 : 0;
    const float* T1p = kpfx + ((size_t)h * L_SEQ + b1i * 64 + 63) * 24;
    const float* T2p = kpfx + ((size_t)h * L_SEQ + b2i * 64 + 63) * 24;
    const float* S2p = kpfx + ((size_t)h * L_SEQ + b2i * 64 + rm1) * 24;
    float f1 = (b >= 1) ? 1.f : 0.f;
    float f2 = (b >= 2) ? 1.f : 0.f;
    float fr = (b >= 2 && r >= 1) ? 1.f : 0.f;
    float psc = 0.f, kcs = 0.f, bnd = 0.f;
#pragma unroll
    for (int m = 0; m < 24; ++m) {
      float qp = qpv[m];
      float kc = kfc[m];
      psc += qp * kc;
      kcs += qp * sKcx[m];
      bnd += qp * (kc + f1 * T1p[m] + f2 * T2p[m] - fr * S2p[m]);
    }
    float goc = kcs + psc;
    float gqk = SCALE_F * bnd;
    float se = sSum[r];
    float lse = __logf(se);
    float gscale = qlog + stab - HLM_F;
    float gln = __logf(fmaxf(goc - gqk, 1e-24f)) + gscale;
    float mx2 = fmaxf(lse, gln), mn2 = fminf(lse, gln);
    float lognorm = mx2 + log1pf(__expf(mn2 - mx2));
    sGps[r] = __expf(gscale - lognorm);
    sRin[r] = 1.f / se;
  }
  __syncthreads();

  // ---- form W (bf16) into old K region ----
  float gpr[4], rin[4];
#pragma unroll
  for (int reg = 0; reg < 4; ++reg) {
    int rl = wv * 16 + g * 4 + reg;
    gpr[reg] = sGps[rl];
    rin[reg] = sRin[rl];
  }
#pragma unroll
  for (int nt = 0; nt < 12; ++nt) {
    int j = nt * 16 + ln;
#pragma unroll
    for (int reg = 0; reg < 4; ++reg) {
      int rl = wv * 16 + g * 4 + reg;
      bool causal = (j >= 128) && (j <= 128 + rl);
      bool bprev = (j >= rl) && (j < 128) && (j >= jmin);
      float coef = causal ? (1.f - SCALE_F) * gpr[reg] : (bprev ? -SCALE_F * gpr[reg] : 0.f);
      float wgt = eF[nt][reg] * rin[reg] + coef * pF[nt][reg];
      float wn = __shfl_xor(wgt, 1);
      if ((ln & 1) == 0) {
        *(unsigned*)(sKW + (rl * 384 + ((j * 2) ^ ((rl & 7) << 4)))) = pk2(wgt, wn);
      }
    }
  }
  __syncthreads();

  // ---- pack KVexcl^T bf16 into sKp (overlaps the WV MFMAs below, no extra barrier yet) ----
  for (int w = t; w < 1024; w += 256) {
    int d = w >> 4, mp = w & 15;
    int m0 = 2 * mp, m1 = m0 + 1;
    float a = (m0 < 24) ? sPfx[m0 * 64 + d] : 0.f;
    float bb = (m1 < 24) ? sPfx[m1 * 64 + d] : 0.f;
    *(unsigned*)(sKp + (d * 64 + ((mp * 4) ^ ((d & 3) << 4)))) = pk2(a, bb);
  }

  // ---- O1 = W * V (192-K): barrier-free, all V^T tiles resident ----
  f32x4 oF[4];
#pragma unroll
  for (int dt = 0; dt < 4; ++dt) { f32x4 z = {0.f, 0.f, 0.f, 0.f}; oF[dt] = z; }
#pragma unroll
  for (int vt3 = 0; vt3 < 3; ++vt3) {
    const char* vbase = sV + vt3 * 8192;
#pragma unroll
    for (int ks = 0; ks < 2; ++ks) {
      short8v aw = *(const short8v*)(sKW + (rA * 384 + ((vt3 * 128 + ks * 64 + g * 16) ^ ((rA & 7) << 4))));
#pragma unroll
      for (int dt = 0; dt < 4; ++dt) {
        int rB = dt * 16 + ln;
        short8v bv = *(const short8v*)(vbase + (rB * 128 + ((ks * 64 + g * 16) ^ ((rB & 7) << 4))));
        oF[dt] = __builtin_amdgcn_mfma_f32_16x16x32_bf16(aw, bv, oF[dt], 0, 0, 0);
      }
    }
  }
  __syncthreads();   // KVexcl pack visible

  // ---- Og = q' * KVexcl ----
  short8v aq = *(const short8v*)(sQp + (rA * 64 + ((g * 16) ^ ((rA & 3) << 4))));
  f32x4 ogF[4];
#pragma unroll
  for (int dt = 0; dt < 4; ++dt) {
    int rB = dt * 16 + ln;
    short8v bg = *(const short8v*)(sKp + (rB * 64 + ((g * 16) ^ ((rB & 3) << 4))));
    f32x4 z = {0.f, 0.f, 0.f, 0.f};
    ogF[dt] = __builtin_amdgcn_mfma_f32_16x16x32_bf16(aq, bg, z, 0, 0, 0);
  }

  // ---- epilogue ----
#pragma unroll
  for (int dt = 0; dt < 4; ++dt) {
    int d = dt * 16 + ln;
#pragma unroll
    for (int reg = 0; reg < 4; ++reg) {
      int rl = wv * 16 + g * 4 + reg;
      int l = b * 64 + rl;
      out[((size_t)l * NH + h) * DH + d] = oF[dt][reg] + gpr[reg] * ogF[dt][reg];
    }
  }
}

extern "C" void kernel_launch(void* const* d_in, const int* in_sizes, int n_in,
                              void* d_out, int out_size, void* d_ws, size_t ws_size,
                              hipStream_t stream)
{
  const float* qkv = (const float*)d_in[0];
  const float* proj = (const float*)d_in[1];
  float* out = (float*)d_out;
  char* ws = (char*)d_ws;

  float* kdash   = (float*)(ws + 0);           // 3145728
  float* qdash   = (float*)(ws + 3145728);     // 3145728
  float* knorm   = (float*)(ws + 6291456);     // 131072
  float* qnorm   = (float*)(ws + 6422528);     // 131072
  float* pmax    = (float*)(ws + 6553600);     // 2048
  unsigned* kbw  = (unsigned*)(ws + 6555648);  // 4194304
  unsigned* qbw  = (unsigned*)(ws + 10749952); // 4194304
  unsigned* kpw  = (unsigned*)(ws + 14944256); // 2097152
  float* kpfx    = (float*)(ws + 17041408);    // 3145728
  unsigned* vtw  = (unsigned*)(ws + 20187136); // 4194304
  float* kvs     = (float*)(ws + 24381440);    // 3145728 (ends at 27527168)

  k1_feat<<<dim3(NCH, NH, 2), 256, 0, stream>>>(qkv, proj, kdash, knorm, qdash, qnorm, pmax, kbw, qbw);
  k3_kprime<<<dim3(NCH, NH), 256, 0, stream>>>(qkv, kdash, knorm, pmax, kpw, kpfx, kvs, vtw);
  k6_attn<<<dim3(NCH, NH), 256, 0, stream>>>(kpw, kpfx, kvs, vtw, qdash, qnorm, pmax, kbw, qbw, out);
}

// Round 11
// 117.542 us; speedup vs baseline: 1.8339x; 1.0207x over previous
//
#include <hip/hip_runtime.h>
#include <hip/hip_bf16.h>

#define L_SEQ 2048
#define NH 16
#define DH 64
#define NCH 32
#define SCALE_F 0.125f
#define EPS_F 1e-4f
#define DN_F 0.35355339059327373f      // sqrt(0.125)
#define HLM_F 1.5890269151739727f      // 0.5*log(24)

typedef __attribute__((ext_vector_type(8))) short short8v;   // 8 bf16 (MFMA A/B frag)
typedef __attribute__((ext_vector_type(4))) float f32x4;     // MFMA C/D frag

// round-to-nearest-even f32 -> bf16
__device__ __forceinline__ unsigned short f2bf(float x) {
  unsigned u = __float_as_uint(x);
  u += 0x7FFFu + ((u >> 16) & 1u);
  return (unsigned short)(u >> 16);
}
__device__ __forceinline__ unsigned pk2(float a, float b) {
  return (unsigned)f2bf(a) | ((unsigned)f2bf(b) << 16);
}
__device__ __forceinline__ float stab_from_pmax(const float* __restrict__ pmax, int h, int t) {
  float v = pmax[h * 32 + (t & 31)];
  v = fmaxf(v, __shfl_xor(v, 1));  v = fmaxf(v, __shfl_xor(v, 2));
  v = fmaxf(v, __shfl_xor(v, 4));  v = fmaxf(v, __shfl_xor(v, 8));
  v = fmaxf(v, __shfl_xor(v, 16));
  return v;
}

// ---------------- K0: all per-chunk feature work (no cross-chunk dependency).
// Produces: pmax, kbw/qbw (bf16 pre-swz), qpw (q' bf16 pre-swz), qpv_g (q' f32),
// qlog_g, a_g = exp(kd-kn-cmax) f32, apfx_g (in-chunk prefix of a),
// avs_g = [Avs[24][64] | Vsum[64]] per chunk, vtw (V^T bf16 pre-swz).
__global__ __launch_bounds__(256) void k0_feat(
    const float* __restrict__ qkv, const float* __restrict__ proj,
    float* __restrict__ pmax, unsigned* __restrict__ kbw, unsigned* __restrict__ qbw,
    unsigned* __restrict__ qpw, float* __restrict__ qpv_g, float* __restrict__ qlog_g,
    float* __restrict__ a_g, float* __restrict__ apfx_g, float* __restrict__ avs_g,
    unsigned* __restrict__ vtw)
{
  __shared__ __attribute__((aligned(16))) float sP[24][68];
  __shared__ __attribute__((aligned(16))) float sX[64][68];
  __shared__ float sA[64][25];
  __shared__ float sRed[256];
  const int c = blockIdx.x, h = blockIdx.y, t = threadIdx.x;
  const int r = t >> 2, mg = t & 3;
  const int l0 = c * 64 + r;
  for (int i = t; i < 1536; i += 256) sP[i >> 6][i & 63] = proj[i];

  // ===== K phase =====
  for (int i = t; i < 1024; i += 256) {
    int rr = i >> 4, d4 = (i & 15) * 4;
    int l = c * 64 + rr;
    *(float4*)&sX[rr][d4] = *(const float4*)(qkv + (((size_t)l * 3 + 1) * NH + h) * DH + d4);
  }
  __syncthreads();
  for (int w = t; w < 2048; w += 256) {
    int rr = w >> 5, wo = w & 31;
    int l = c * 64 + rr;
    float2 xv = *(const float2*)&sX[rr][2 * wo];
    kbw[((size_t)h * L_SEQ + l) * 32 + (wo ^ ((rr & 7) << 2))] = pk2(xv.x, xv.y);
  }
  float acc[6] = {0.f, 0.f, 0.f, 0.f, 0.f, 0.f};
  float sq = 0.f;
  for (int d4 = 0; d4 < 16; ++d4) {
    float4 xv = *(const float4*)&sX[r][d4 * 4];
    sq += xv.x * xv.x; sq += xv.y * xv.y; sq += xv.z * xv.z; sq += xv.w * xv.w;
#pragma unroll
    for (int i = 0; i < 6; ++i) {
      float4 pv = *(const float4*)&sP[mg * 6 + i][d4 * 4];
      acc[i] += xv.x * pv.x; acc[i] += xv.y * pv.y;
      acc[i] += xv.z * pv.z; acc[i] += xv.w * pv.w;
    }
  }
  float kd[6]; float lmax = -1e30f;
#pragma unroll
  for (int i = 0; i < 6; ++i) { kd[i] = acc[i] * DN_F; lmax = fmaxf(lmax, kd[i]); }
  const float kn = 0.5f * SCALE_F * sq;
  sRed[t] = lmax;
  __syncthreads();
#pragma unroll
  for (int s = 128; s > 0; s >>= 1) {
    if (t < s) sRed[t] = fmaxf(sRed[t], sRed[t + s]);
    __syncthreads();
  }
  const float cmax = sRed[0];
  if (t == 0) pmax[h * 32 + c] = cmax;
#pragma unroll
  for (int i = 0; i < 6; ++i) {
    float av = __expf(kd[i] - kn - cmax);
    sA[r][mg * 6 + i] = av;
    a_g[((size_t)h * L_SEQ + l0) * 24 + mg * 6 + i] = av;
  }

  // ===== Q phase (sX reuse: all K reads finished before the tree barrier) =====
  for (int i = t; i < 1024; i += 256) {
    int rr = i >> 4, d4 = (i & 15) * 4;
    int l = c * 64 + rr;
    *(float4*)&sX[rr][d4] = *(const float4*)(qkv + (((size_t)l * 3 + 0) * NH + h) * DH + d4);
  }
  __syncthreads();
  for (int w = t; w < 2048; w += 256) {
    int rr = w >> 5, wo = w & 31;
    int l = c * 64 + rr;
    float2 xv = *(const float2*)&sX[rr][2 * wo];
    qbw[((size_t)h * L_SEQ + l) * 32 + (wo ^ ((rr & 7) << 2))] = pk2(xv.x, xv.y);
  }
  float qacc[6] = {0.f, 0.f, 0.f, 0.f, 0.f, 0.f};
  float qsq = 0.f;
  for (int d4 = 0; d4 < 16; ++d4) {
    float4 xv = *(const float4*)&sX[r][d4 * 4];
    qsq += xv.x * xv.x; qsq += xv.y * xv.y; qsq += xv.z * xv.z; qsq += xv.w * xv.w;
#pragma unroll
    for (int i = 0; i < 6; ++i) {
      float4 pv = *(const float4*)&sP[mg * 6 + i][d4 * 4];
      qacc[i] += xv.x * pv.x; qacc[i] += xv.y * pv.y;
      qacc[i] += xv.z * pv.z; qacc[i] += xv.w * pv.w;
    }
  }
  float qd6[6]; float qmx = -1e30f;
#pragma unroll
  for (int i = 0; i < 6; ++i) { qd6[i] = qacc[i] * DN_F; qmx = fmaxf(qmx, qd6[i]); }
  qmx = fmaxf(qmx, __shfl_xor(qmx, 1));
  qmx = fmaxf(qmx, __shfl_xor(qmx, 2));     // exact row max across the quad
  float qp6[6];
#pragma unroll
  for (int i = 0; i < 6; ++i) {
    qp6[i] = __expf(qd6[i] - qmx) + EPS_F;
    qpv_g[((size_t)h * L_SEQ + l0) * 24 + mg * 6 + i] = qp6[i];
  }
#pragma unroll
  for (int j = 0; j < 3; ++j)
    qpw[((size_t)h * L_SEQ + l0) * 16 + ((3 * mg + j) ^ ((r & 3) << 2))] = pk2(qp6[2 * j], qp6[2 * j + 1]);
  if (mg == 0) {
#pragma unroll
    for (int j = 0; j < 4; ++j)
      qpw[((size_t)h * L_SEQ + l0) * 16 + ((12 + j) ^ ((r & 3) << 2))] = 0u;
    qlog_g[(size_t)h * L_SEQ + l0] = qmx - 0.5f * SCALE_F * qsq - HLM_F;
  }

  // ===== V phase =====
  __syncthreads();   // all Q reads of sX done
  for (int i = t; i < 1024; i += 256) {
    int rr = i >> 4, d4 = (i & 15) * 4;
    int l = c * 64 + rr;
    *(float4*)&sX[rr][d4] = *(const float4*)(qkv + (((size_t)l * 3 + 2) * NH + h) * DH + d4);
  }
  __syncthreads();
  for (int w = t; w < 2048; w += 256) {
    int d = w >> 5, jp = w & 31;
    vtw[((size_t)h * NCH + c) * 2048 + d * 32 + (jp ^ ((d & 7) << 2))] = pk2(sX[2 * jp][d], sX[2 * jp + 1][d]);
  }
  if (t < 192) {
    const int m = t % 24, dO = (t / 24) * 8;
    float a0x = 0.f, a0y = 0.f, a0z = 0.f, a0w = 0.f;
    float a1x = 0.f, a1y = 0.f, a1z = 0.f, a1w = 0.f;
    for (int r2 = 0; r2 < 64; ++r2) {
      float kp = sA[r2][m];
      float4 v0 = *(const float4*)&sX[r2][dO];
      float4 v1 = *(const float4*)&sX[r2][dO + 4];
      a0x += kp * v0.x; a0y += kp * v0.y; a0z += kp * v0.z; a0w += kp * v0.w;
      a1x += kp * v1.x; a1y += kp * v1.y; a1z += kp * v1.z; a1w += kp * v1.w;
    }
    float* dst = avs_g + ((size_t)h * NCH + c) * 1600 + m * 64 + dO;
    float4 o0 = {a0x, a0y, a0z, a0w};
    float4 o1 = {a1x, a1y, a1z, a1w};
    *(float4*)dst = o0;
    *(float4*)(dst + 4) = o1;
  } else {
    int m = t - 192;
    if (m < 24) {
      float run = 0.f;
      for (int r2 = 0; r2 < 64; ++r2) {
        run += sA[r2][m];
        apfx_g[((size_t)h * L_SEQ + c * 64 + r2) * 24 + m] = run;
      }
    }
    int d = t - 192;   // 0..63
    float vs = 0.f;
    for (int r2 = 0; r2 < 64; ++r2) vs += sX[r2][d];
    avs_g[((size_t)h * NCH + c) * 1600 + 1536 + d] = vs;
  }
}

// ---------------- K6: fused banded + performer attention; reconstructs k'-derived
// quantities via k' = s_c * a + EPS, s_c = exp(pmax[c] - stab).
__global__ __launch_bounds__(256, 2) void k6_attn(
    const float* __restrict__ pmax, const unsigned* __restrict__ kbw,
    const unsigned* __restrict__ qbw, const unsigned* __restrict__ qpw,
    const float* __restrict__ qpv_g, const float* __restrict__ qlog_g,
    const float* __restrict__ a_g, const float* __restrict__ apfx_g,
    const float* __restrict__ avs_g, const unsigned* __restrict__ vtw,
    float* __restrict__ out)
{
  __shared__ __attribute__((aligned(16))) char lds[80992];
  char* sKW = lds;                       // 24576: K [192][128B]; later W [64][384B]
  char* sKp = lds + 24576;               // 12288: k' [192][64B]; later KVexcl^T [64][64B]
  char* sV  = lds + 36864;               // 24576: V^T tiles [3][64][128B]
  char* sQ  = lds + 61440;               // 8192:  Q [64][128B]
  char* sQp = lds + 69632;               // 4096:  q' [64][64B]
  float* sSum = (float*)(lds + 73728);   // 64
  float* sGps = (float*)(lds + 73984);   // 64
  float* sRin = (float*)(lds + 74240);   // 64
  float* sKcx = (float*)(lds + 74496);   // 24 used
  float* sVx  = (float*)(lds + 74592);   // 64: EPS-side of KVexcl
  float* sPfx = (float*)(lds + 74848);   // [1536] f32 sum of s_c*Avs -> ends 80992

  const int b = blockIdx.x, h = blockIdx.y, t = threadIdx.x;
  const int wv = t >> 6, lane = t & 63, g = lane >> 4, ln = lane & 15;
  const int keybase = b * 64 - 128;
  const int jmin = (b >= 2) ? 0 : (128 - 64 * b);
  const int rA = wv * 16 + ln;
  const float stab = stab_from_pmax(pmax, h, t);

  // ---- stage K / Q / q' / V^T (pure uint4 copies of pre-swizzled bf16) ----
  for (int w = t; w < 1536; w += 256) {          // K 192 rows
    int r = w >> 3, q4 = w & 7;
    int l = keybase + r; l = l < 0 ? 0 : l;
    *(uint4*)(sKW + r * 128 + q4 * 16) = *(const uint4*)(kbw + ((size_t)h * L_SEQ + l) * 32 + q4 * 4);
  }
  for (int w = t; w < 512; w += 256) {           // Q 64 rows
    int r = w >> 3, q4 = w & 7;
    int l = b * 64 + r;
    *(uint4*)(sQ + r * 128 + q4 * 16) = *(const uint4*)(qbw + ((size_t)h * L_SEQ + l) * 32 + q4 * 4);
  }
  for (int w = t; w < 256; w += 256) {           // q' 64 rows x 4 uint4
    int r = w >> 2, q4 = w & 3;
    int l = b * 64 + r;
    *(uint4*)(sQp + r * 64 + q4 * 16) = *(const uint4*)(qpw + ((size_t)h * L_SEQ + l) * 16 + q4 * 4);
  }
  for (int w = t; w < 1536; w += 256) {          // V^T 3 tiles
    int vt = w >> 9, idx = w & 511;
    int lt = b - 2 + vt; lt = lt < 0 ? 0 : lt;
    *(uint4*)(sV + vt * 8192 + idx * 16) = *(const uint4*)(vtw + ((size_t)h * NCH + lt) * 2048 + idx * 4);
  }
  // ---- k' = fma(s_c, a, EPS) -> bf16 swizzled into sKp ----
  for (int w = t; w < 2304; w += 256) {          // 192 rows x 12 word-pairs
    int r = w / 12, p = w % 12;
    int l = keybase + r; l = l < 0 ? 0 : l;
    float s = __expf(pmax[h * 32 + (l >> 6)] - stab);
    const float* ap = a_g + ((size_t)h * L_SEQ + l) * 24 + 2 * p;
    float k0v = fmaf(s, ap[0], EPS_F);
    float k1v = fmaf(s, ap[1], EPS_F);
    *(unsigned*)(sKp + (r * 64 + 4 * (p ^ ((r & 3) << 2)))) = pk2(k0v, k1v);
  }
  for (int w = t; w < 768; w += 256) {           // zero pad words 12..15
    int r = w >> 2, p = 12 + (w & 3);
    *(unsigned*)(sKp + (r * 64 + 4 * (p ^ ((r & 3) << 2)))) = 0u;
  }
  // ---- KVexcl pieces: sPfx = sum s_c*Avs, sVx = sum Vsum (unroll 4) ----
  {
    float accp[6] = {0.f, 0.f, 0.f, 0.f, 0.f, 0.f};
    float vexc = 0.f;
    const float* srcb = avs_g + (size_t)h * NCH * 1600;
    int bp = 0;
    for (; bp + 4 <= b; bp += 4) {
      float s0 = __expf(pmax[h * 32 + bp + 0] - stab);
      float s1 = __expf(pmax[h * 32 + bp + 1] - stab);
      float s2 = __expf(pmax[h * 32 + bp + 2] - stab);
      float s3 = __expf(pmax[h * 32 + bp + 3] - stab);
      float v0[6], v1[6], v2[6], v3[6];
#pragma unroll
      for (int j = 0; j < 6; ++j) v0[j] = srcb[(size_t)(bp + 0) * 1600 + t + j * 256];
#pragma unroll
      for (int j = 0; j < 6; ++j) v1[j] = srcb[(size_t)(bp + 1) * 1600 + t + j * 256];
#pragma unroll
      for (int j = 0; j < 6; ++j) v2[j] = srcb[(size_t)(bp + 2) * 1600 + t + j * 256];
#pragma unroll
      for (int j = 0; j < 6; ++j) v3[j] = srcb[(size_t)(bp + 3) * 1600 + t + j * 256];
      float w0 = 0.f, w1 = 0.f, w2 = 0.f, w3 = 0.f;
      if (t < 64) {
        w0 = srcb[(size_t)(bp + 0) * 1600 + 1536 + t];
        w1 = srcb[(size_t)(bp + 1) * 1600 + 1536 + t];
        w2 = srcb[(size_t)(bp + 2) * 1600 + 1536 + t];
        w3 = srcb[(size_t)(bp + 3) * 1600 + 1536 + t];
      }
#pragma unroll
      for (int j = 0; j < 6; ++j) {
        accp[j] = fmaf(s0, v0[j], accp[j]); accp[j] = fmaf(s1, v1[j], accp[j]);
        accp[j] = fmaf(s2, v2[j], accp[j]); accp[j] = fmaf(s3, v3[j], accp[j]);
      }
      if (t < 64) { vexc += w0; vexc += w1; vexc += w2; vexc += w3; }
    }
    for (; bp < b; ++bp) {
      float s = __expf(pmax[h * 32 + bp] - stab);
#pragma unroll
      for (int j = 0; j < 6; ++j) accp[j] = fmaf(s, srcb[(size_t)bp * 1600 + t + j * 256], accp[j]);
      if (t < 64) vexc += srcb[(size_t)bp * 1600 + 1536 + t];
    }
#pragma unroll
    for (int j = 0; j < 6; ++j) sPfx[t + j * 256] = accp[j];
    if (t < 64) sVx[t] = vexc;
  }
  if (t < 24) {
    float runk = 0.f;
    for (int bp = 0; bp < b; ++bp) {
      float s = __expf(pmax[h * 32 + bp] - stab);
      runk = fmaf(s, apfx_g[((size_t)h * L_SEQ + bp * 64 + 63) * 24 + t], runk);
    }
    sKcx[t] = runk + EPS_F * 64.f * (float)b;
  }
  // ---- q' stats load (f32, precomputed) ----
  float qlog = 0.f;
  float qpv[24];
  if (t < 64) {
    int l = b * 64 + t;
    const float* qdp = qpv_g + ((size_t)h * L_SEQ + l) * 24;
#pragma unroll
    for (int i = 0; i < 6; ++i) {
      float4 v = *(const float4*)(qdp + 4 * i);
      qpv[4 * i] = v.x; qpv[4 * i + 1] = v.y; qpv[4 * i + 2] = v.z; qpv[4 * i + 3] = v.w;
    }
    qlog = qlog_g[(size_t)h * L_SEQ + l];
  }
  __syncthreads();

  // ---- S = Q K^T (masked exp), wave-local row sums ----
  float eF[12][4];
  float rs[4] = {0.f, 0.f, 0.f, 0.f};
  short8v aS0 = *(const short8v*)(sQ + (rA * 128 + ((g * 16) ^ ((rA & 7) << 4))));
  short8v aS1 = *(const short8v*)(sQ + (rA * 128 + ((64 + g * 16) ^ ((rA & 7) << 4))));
#pragma unroll
  for (int nt = 0; nt < 12; ++nt) {
    int rB = nt * 16 + ln;
    short8v b0 = *(const short8v*)(sKW + (rB * 128 + ((g * 16) ^ ((rB & 7) << 4))));
    short8v b1 = *(const short8v*)(sKW + (rB * 128 + ((64 + g * 16) ^ ((rB & 7) << 4))));
    f32x4 acc = {0.f, 0.f, 0.f, 0.f};
    acc = __builtin_amdgcn_mfma_f32_16x16x32_bf16(aS0, b0, acc, 0, 0, 0);
    acc = __builtin_amdgcn_mfma_f32_16x16x32_bf16(aS1, b1, acc, 0, 0, 0);
    int j = nt * 16 + ln;
#pragma unroll
    for (int reg = 0; reg < 4; ++reg) {
      int rl = wv * 16 + g * 4 + reg;
      float e = 0.f;
      if (j >= rl && j <= rl + 128 && j >= jmin) e = __expf(SCALE_F * acc[reg]);
      eF[nt][reg] = e;
      rs[reg] += e;
    }
  }
#pragma unroll
  for (int reg = 0; reg < 4; ++reg) {
    float v = rs[reg];
    v += __shfl_xor(v, 1); v += __shfl_xor(v, 2);
    v += __shfl_xor(v, 4); v += __shfl_xor(v, 8);
    if (ln == 0) sSum[wv * 16 + g * 4 + reg] = v;
  }

  // ---- P = q' k'^T ----
  float pF[12][4];
  short8v aP = *(const short8v*)(sQp + (rA * 64 + ((g * 16) ^ ((rA & 3) << 4))));
#pragma unroll
  for (int nt = 0; nt < 12; ++nt) {
    int rB = nt * 16 + ln;
    short8v bp = *(const short8v*)(sKp + (rB * 64 + ((g * 16) ^ ((rB & 3) << 4))));
    f32x4 acc = {0.f, 0.f, 0.f, 0.f};
    acc = __builtin_amdgcn_mfma_f32_16x16x32_bf16(aP, bp, acc, 0, 0, 0);
#pragma unroll
    for (int reg = 0; reg < 4; ++reg) pF[nt][reg] = acc[reg];
  }
  __syncthreads();

  // ---- per-row stats (kpfx values reconstructed: s*apfx + EPS*count) ----
  if (t < 64) {
    int r = t, l = b * 64 + r;
    const float* apO = apfx_g + ((size_t)h * L_SEQ + l) * 24;
    int b1i = (b >= 1) ? b - 1 : 0;
    int b2i = (b >= 2) ? b - 2 : 0;
    int rm1 = (r >= 1) ? r - 1 : 0;
    const float* T1a = apfx_g + ((size_t)h * L_SEQ + b1i * 64 + 63) * 24;
    const float* T2a = apfx_g + ((size_t)h * L_SEQ + b2i * 64 + 63) * 24;
    const float* S2a = apfx_g + ((size_t)h * L_SEQ + b2i * 64 + rm1) * 24;
    float f1 = (b >= 1) ? 1.f : 0.f;
    float f2 = (b >= 2) ? 1.f : 0.f;
    float fr = (b >= 2 && r >= 1) ? 1.f : 0.f;
    float sb = __expf(pmax[h * 32 + b] - stab);
    float s1 = __expf(pmax[h * 32 + b1i] - stab);
    float s2 = __expf(pmax[h * 32 + b2i] - stab);
    float cEr = EPS_F * (float)(r + 1), cE64 = EPS_F * 64.f, cEr1 = EPS_F * (float)(rm1 + 1);
    float psc = 0.f, kcs = 0.f, bnd = 0.f;
#pragma unroll
    for (int m = 0; m < 24; ++m) {
      float qp = qpv[m];
      float kc  = fmaf(sb, apO[m], cEr);
      float t1v = fmaf(s1, T1a[m], cE64);
      float t2v = fmaf(s2, T2a[m], cE64);
      float s2v = fmaf(s2, S2a[m], cEr1);
      psc += qp * kc;
      kcs += qp * sKcx[m];
      bnd += qp * (kc + f1 * t1v + f2 * t2v - fr * s2v);
    }
    float goc = kcs + psc;
    float gqk = SCALE_F * bnd;
    float se = sSum[r];
    float lse = __logf(se);
    float gscale = qlog + stab - HLM_F;
    float gln = __logf(fmaxf(goc - gqk, 1e-24f)) + gscale;
    float mx2 = fmaxf(lse, gln), mn2 = fminf(lse, gln);
    float lognorm = mx2 + log1pf(__expf(mn2 - mx2));
    sGps[r] = __expf(gscale - lognorm);
    sRin[r] = 1.f / se;
  }
  __syncthreads();

  // ---- form W (bf16) into old K region ----
  float gpr[4], rin[4];
#pragma unroll
  for (int reg = 0; reg < 4; ++reg) {
    int rl = wv * 16 + g * 4 + reg;
    gpr[reg] = sGps[rl];
    rin[reg] = sRin[rl];
  }
#pragma unroll
  for (int nt = 0; nt < 12; ++nt) {
    int j = nt * 16 + ln;
#pragma unroll
    for (int reg = 0; reg < 4; ++reg) {
      int rl = wv * 16 + g * 4 + reg;
      bool causal = (j >= 128) && (j <= 128 + rl);
      bool bprev = (j >= rl) && (j < 128) && (j >= jmin);
      float coef = causal ? (1.f - SCALE_F) * gpr[reg] : (bprev ? -SCALE_F * gpr[reg] : 0.f);
      float wgt = eF[nt][reg] * rin[reg] + coef * pF[nt][reg];
      float wn = __shfl_xor(wgt, 1);
      if ((ln & 1) == 0) {
        *(unsigned*)(sKW + (rl * 384 + ((j * 2) ^ ((rl & 7) << 4)))) = pk2(wgt, wn);
      }
    }
  }
  __syncthreads();

  // ---- pack KVexcl^T bf16 into sKp: s-weighted Avs sum + EPS * Vsum ----
  for (int w = t; w < 1024; w += 256) {
    int d = w >> 4, mp = w & 15;
    int m0 = 2 * mp, m1 = m0 + 1;
    float base = EPS_F * sVx[d];
    float a = (m0 < 24) ? sPfx[m0 * 64 + d] + base : 0.f;
    float bb = (m1 < 24) ? sPfx[m1 * 64 + d] + base : 0.f;
    *(unsigned*)(sKp + (d * 64 + ((mp * 4) ^ ((d & 3) << 4)))) = pk2(a, bb);
  }

  // ---- O1 = W * V (192-K): barrier-free, all V^T tiles resident ----
  f32x4 oF[4];
#pragma unroll
  for (int dt = 0; dt < 4; ++dt) { f32x4 z = {0.f, 0.f, 0.f, 0.f}; oF[dt] = z; }
#pragma unroll
  for (int vt3 = 0; vt3 < 3; ++vt3) {
    const char* vbase = sV + vt3 * 8192;
#pragma unroll
    for (int ks = 0; ks < 2; ++ks) {
      short8v aw = *(const short8v*)(sKW + (rA * 384 + ((vt3 * 128 + ks * 64 + g * 16) ^ ((rA & 7) << 4))));
#pragma unroll
      for (int dt = 0; dt < 4; ++dt) {
        int rB = dt * 16 + ln;
        short8v bv = *(const short8v*)(vbase + (rB * 128 + ((ks * 64 + g * 16) ^ ((rB & 7) << 4))));
        oF[dt] = __builtin_amdgcn_mfma_f32_16x16x32_bf16(aw, bv, oF[dt], 0, 0, 0);
      }
    }
  }
  __syncthreads();   // KVexcl pack visible

  // ---- Og = q' * KVexcl ----
  short8v aq = *(const short8v*)(sQp + (rA * 64 + ((g * 16) ^ ((rA & 3) << 4))));
  f32x4 ogF[4];
#pragma unroll
  for (int dt = 0; dt < 4; ++dt) {
    int rB = dt * 16 + ln;
    short8v bg = *(const short8v*)(sKp + (rB * 64 + ((g * 16) ^ ((rB & 3) << 4))));
    f32x4 z = {0.f, 0.f, 0.f, 0.f};
    ogF[dt] = __builtin_amdgcn_mfma_f32_16x16x32_bf16(aq, bg, z, 0, 0, 0);
  }

  // ---- epilogue ----
#pragma unroll
  for (int dt = 0; dt < 4; ++dt) {
    int d = dt * 16 + ln;
#pragma unroll
    for (int reg = 0; reg < 4; ++reg) {
      int rl = wv * 16 + g * 4 + reg;
      int l = b * 64 + rl;
      out[((size_t)l * NH + h) * DH + d] = oF[dt][reg] + gpr[reg] * ogF[dt][reg];
    }
  }
}

extern "C" void kernel_launch(void* const* d_in, const int* in_sizes, int n_in,
                              void* d_out, int out_size, void* d_ws, size_t ws_size,
                              hipStream_t stream)
{
  const float* qkv = (const float*)d_in[0];
  const float* proj = (const float*)d_in[1];
  float* out = (float*)d_out;
  char* ws = (char*)d_ws;

  float* pmax    = (float*)(ws + 0);           // 2048 (pad to 4096)
  unsigned* kbw  = (unsigned*)(ws + 4096);     // 4194304
  unsigned* qbw  = (unsigned*)(ws + 4198400);  // 4194304
  unsigned* qpw  = (unsigned*)(ws + 8392704);  // 2097152
  float* qpv_g   = (float*)(ws + 10489856);    // 3145728
  float* qlog_g  = (float*)(ws + 13635584);    // 131072
  float* a_g     = (float*)(ws + 13766656);    // 3145728
  float* apfx_g  = (float*)(ws + 16912384);    // 3145728
  float* avs_g   = (float*)(ws + 20058112);    // 3276800 (16*32*1600*4)
  unsigned* vtw  = (unsigned*)(ws + 23334912); // 4194304 -> ends 27529216

  k0_feat<<<dim3(NCH, NH), 256, 0, stream>>>(qkv, proj, pmax, kbw, qbw, qpw,
                                             qpv_g, qlog_g, a_g, apfx_g, avs_g, vtw);
  k6_attn<<<dim3(NCH, NH), 256, 0, stream>>>(pmax, kbw, qbw, qpw, qpv_g, qlog_g,
                                             a_g, apfx_g, avs_g, vtw, out);
}